// Round 4
// baseline (172.609 us; speedup 1.0000x reference)
//
#include <hip/hip_runtime.h>
#include <hip/hip_bf16.h>

// Round-2 finding: ALL inputs and the output are FP32.
// Round-14: qkv/proj converted to bf16 MFMA GEMMs (-33us).
// Round-15/16: coalesced xpose/wpack; fragment-tiled xb2 (-17us).
// Round-17 (this): attn was serialization-bound (~45us vs ~5us MFMA
// arithmetic): per-32-key chunk the chain ds_read->QK->exp->P-write->
// lgkmcnt(0)->P-read->PV->barrier is fully serial, x32 chunks.  Restructure:
//   - 64-key iterations (16 iters, half the barriers, 2x work per sync)
//   - deferred PV: PV(t) consumes P(t-1), already drained by the previous
//     barrier -> no intra-iteration LDS stall; QK(t) || PV(t-1) gives 10
//     independent MFMAs per iter.  V frags carried in registers.
//   - P double-buffer aliased over the dead Gw region; LDS 44.5KB,
//     3 blocks/CU (launch_bounds 256,3).

typedef __hip_bfloat16 bf16;
using short8 = __attribute__((ext_vector_type(8))) short;
using short4v = __attribute__((ext_vector_type(4))) short;
using f32x4 = __attribute__((ext_vector_type(4))) float;

__device__ __forceinline__ short f2bs(float f) {
  union { bf16 b; short s; } u; u.b = __float2bfloat16(f); return u.s;
}
__device__ __forceinline__ float bs2f(short s) {
  union { unsigned u; float f; } x; x.u = ((unsigned)(unsigned short)s) << 16;
  return x.f;
}

// ---------------------------------------------------------------------------
// Prepass A (v4): LDS-transpose repack.
//   xt[b][34][34][256] bf16: spatial-major channel-contig with zero halo.
//   xb2[b][pb][c8][grp][pcol][8] bf16: MFMA-fragment-tiled.
// grid (8, 34), block 256.
// ---------------------------------------------------------------------------
__global__ __launch_bounds__(256) void xpose(
    const float* __restrict__ X, short* __restrict__ xt,
    short* __restrict__ xb2) {
  const int b = blockIdx.x, r = blockIdx.y;   // r in 0..33 (halo coords)
  const int tid = threadIdx.x;
  if (r == 0 || r == 33) {                    // full zero halo row
    short8 z = {};
    short* dst = xt + (((size_t)b * 34 + r) * 34) * 256;
    for (int g = tid; g < 1088; g += 256) *(short8*)(dst + g * 8) = z;
    return;
  }
  __shared__ short xls[32][264];              // [p][c], pitch 264
  {
    const float* src = X + (size_t)b * 256 * 1024 + (r - 1) * 32;
    for (int it = 0; it < 8; ++it) {
      int idx = it * 256 + tid;
      int c = idx >> 3, pq = idx & 7;
      float4 f4 = *(const float4*)(src + (size_t)c * 1024 + pq * 4);
      xls[pq * 4 + 0][c] = f2bs(f4.x);
      xls[pq * 4 + 1][c] = f2bs(f4.y);
      xls[pq * 4 + 2][c] = f2bs(f4.z);
      xls[pq * 4 + 3][c] = f2bs(f4.w);
    }
  }
  __syncthreads();
  {
    short* dst = xt + (((size_t)b * 34 + r) * 34) * 256;
    for (int it = 0; it < 4; ++it) {
      int idx = it * 256 + tid;
      int cc = idx >> 5, co = idx & 31;
      short8 v = *(const short8*)&xls[cc][co * 8];
      *(short8*)(dst + (cc + 1) * 256 + co * 8) = v;
    }
    if (tid < 64) {
      short8 z = {};
      int cce = (tid >> 5) * 33, co = tid & 31;
      *(short8*)(dst + cce * 256 + co * 8) = z;
    }
  }
  {
    short* dst = xb2 + (((size_t)b * 64 + (r - 1) * 2) * 8) * 512;
    for (int it = 0; it < 4; ++it) {
      int g = it * 256 + tid;
      int half = g >> 9, c8 = (g >> 6) & 7, grp = (g >> 4) & 3, pcol = g & 15;
      short8 v = *(const short8*)&xls[half * 16 + pcol][c8 * 32 + grp * 8];
      *(short8*)(dst + ((half * 8 + c8) * 64 + grp * 16 + pcol) * 8) = v;
    }
  }
}

// ---------------------------------------------------------------------------
// Prepass B (v2): coalesced weight packs.  grid 1280, block 256.
// ---------------------------------------------------------------------------
__global__ __launch_bounds__(256) void wpack(
    const float* __restrict__ Wc, short* __restrict__ Wb,
    const float* __restrict__ wq, short* __restrict__ Wq,
    const float* __restrict__ wa, short* __restrict__ Wa) {
  const int bid = blockIdx.x;
  const int tid = threadIdx.x;
  if (bid < 256) {
    __shared__ float ws[2304];                 // one o's [c][tap] block
    const float* src = Wc + (size_t)bid * 2304;
    for (int it = 0; it < 9; ++it) ws[it * 256 + tid] = src[it * 256 + tid];
    __syncthreads();
#pragma unroll
    for (int tap = 0; tap < 9; ++tap)          // bank-free: 9 coprime 32
      Wb[tap * 65536 + bid * 256 + tid] = f2bs(ws[tid * 9 + tap]);
  } else if (bid < 1024) {
    int idx = (bid - 256) * 256 + tid;
    Wq[idx] = f2bs(wq[idx]);
  } else {
    int idx = (bid - 1024) * 256 + tid;
    Wa[idx] = f2bs(wa[idx]);
  }
}

// ---------------------------------------------------------------------------
// Kernel 1 (v9): QKV 1x1 conv as bf16 MFMA GEMM (unchanged this round).
// grid (16, 6, 8), block 256.
// ---------------------------------------------------------------------------
__global__ __launch_bounds__(256) void qkv_mfma(
    const short* __restrict__ Wq, const short* __restrict__ xb2,
    const float* __restrict__ bias,
    short* __restrict__ qsb, short* __restrict__ ksb, short* __restrict__ vtb) {
  const int tid = threadIdx.x;
  const int w = tid >> 6, lane = tid & 63;
  const int col = lane & 15, grp = lane >> 4, g8 = grp * 8;
  const int b = blockIdx.z;
  const int p0 = blockIdx.x * 64;
  const int og = blockIdx.y * 128;
  const int ob = og + w * 16;

  const short* wa0 = Wq + (size_t)(ob + col) * 256 + g8;
  const short* wa1 = wa0 + (size_t)64 * 256;
  const short* xpb = xb2 + (((size_t)b * 64 + blockIdx.x * 4) * 8) * 512 + lane * 8;

  f32x4 acc[2][4] = {};
#pragma unroll
  for (int c8 = 0; c8 < 8; ++c8) {
    const int chb = c8 * 32;
    short8 a0 = *(const short8*)(wa0 + chb);
    short8 a1 = *(const short8*)(wa1 + chb);
    short8 b0 = *(const short8*)(xpb + c8 * 512);
    short8 b1 = *(const short8*)(xpb + 4096 + c8 * 512);
    short8 b2 = *(const short8*)(xpb + 8192 + c8 * 512);
    short8 b3 = *(const short8*)(xpb + 12288 + c8 * 512);
    acc[0][0] = __builtin_amdgcn_mfma_f32_16x16x32_bf16(a0, b0, acc[0][0], 0, 0, 0);
    acc[0][1] = __builtin_amdgcn_mfma_f32_16x16x32_bf16(a0, b1, acc[0][1], 0, 0, 0);
    acc[0][2] = __builtin_amdgcn_mfma_f32_16x16x32_bf16(a0, b2, acc[0][2], 0, 0, 0);
    acc[0][3] = __builtin_amdgcn_mfma_f32_16x16x32_bf16(a0, b3, acc[0][3], 0, 0, 0);
    acc[1][0] = __builtin_amdgcn_mfma_f32_16x16x32_bf16(a1, b0, acc[1][0], 0, 0, 0);
    acc[1][1] = __builtin_amdgcn_mfma_f32_16x16x32_bf16(a1, b1, acc[1][1], 0, 0, 0);
    acc[1][2] = __builtin_amdgcn_mfma_f32_16x16x32_bf16(a1, b2, acc[1][2], 0, 0, 0);
    acc[1][3] = __builtin_amdgcn_mfma_f32_16x16x32_bf16(a1, b3, acc[1][3], 0, 0, 0);
  }

  const float qscale = 0.17677669529663687f;  // 32^-0.5
#pragma unroll
  for (int j = 0; j < 2; ++j) {
    const int obase = ob + j * 64 + grp * 4;   // + r gives the output chan
    const int sect = obase >> 8;               // 0=q 1=k 2=v (tile-uniform)
    const int nh = (obase >> 5) & 7;
    const int d0 = obase & 31;                 // d0..d0+3 consecutive
    const size_t hb = ((size_t)(b * 8 + nh)) * 1024;
    float bv[4];
#pragma unroll
    for (int r = 0; r < 4; ++r) bv[r] = bias[obase + r];
    if (sect == 0) {
#pragma unroll
      for (int pp = 0; pp < 4; ++pp) {
        const int p = p0 + pp * 16 + col;
        short4v o4;
#pragma unroll
        for (int r = 0; r < 4; ++r)
          o4[r] = f2bs((acc[j][pp][r] + bv[r]) * qscale);
        *(short4v*)&qsb[(hb + p) * 32 + d0] = o4;
      }
    } else if (sect == 1) {
#pragma unroll
      for (int pp = 0; pp < 4; ++pp) {
        const int p = p0 + pp * 16 + col;
        short4v o4;
#pragma unroll
        for (int r = 0; r < 4; ++r)
          o4[r] = f2bs(acc[j][pp][r] + bv[r]);
        *(short4v*)&ksb[(hb + p) * 32 + d0] = o4;
      }
    } else {
#pragma unroll
      for (int pp = 0; pp < 4; ++pp) {
        const int p = p0 + pp * 16 + col;
#pragma unroll
        for (int r = 0; r < 4; ++r)
          vtb[hb * 32 + (size_t)(d0 + r) * 1024 + p] = f2bs(acc[j][pp][r] + bv[r]);
      }
    }
  }
}

// ---------------------------------------------------------------------------
// Kernel 2 (v8): pipelined transposed MFMA flash attention.
// grid (16, 64), block 256 = 4 waves; 1 wave = 16 q x 1024 keys.
// Per 64-key iteration: wave w stages K-frag w + V-frag 4+w into kvb[next];
// all waves read 8 frags lane-linear; QK(t) computed alongside PV(t-1)
// (P(t-1) was drained by the previous barrier; V(t-1) carried in regs);
// one __syncthreads per iteration.
// ---------------------------------------------------------------------------
__global__ __launch_bounds__(256, 3) void attn_mfma(
    const short* __restrict__ qsb, const short* __restrict__ ksb,
    const short* __restrict__ vtb,
    const float* __restrict__ relw_g, const float* __restrict__ relh_g,
    short* __restrict__ amt) {
  const int tid = threadIdx.x;
  const int w = tid >> 6, lane = tid & 63;
  const int col = lane & 15, grp = lane >> 4, g8 = grp * 8;
  const int qt = blockIdx.x * 4 + w;       // q-tile 0..63
  const int bnh = blockIdx.y;
  const int q0 = qt * 16;
  const int i = qt >> 1;                   // query row, constant per wave
  const int j0 = (qt & 1) * 16;            // query col base

  const short* Qb = qsb + (size_t)bnh * 32768;
  const short* Kb = ksb + (size_t)bnh * 32768;
  const short* Vb = vtb + (size_t)bnh * 32768;

  __shared__ short Gh_s[4][16][68];        // [wave][q][m]       8704B
  __shared__ short kvb[2][8][512];         // [slot][frag][...] 16384B
  __shared__ short Pt_s[4][2][2][16][40];  // [wave][slot][half][q][key] 20480B
  // Gw region aliased over this wave's Pt_s (dead after gw[] preload,
  // which completes before the first barrier / first Pt write).
  short* Gw_w = &Pt_s[w][0][0][0][0];      // pitch 68, needs 1088 <= 1280 ok

  // staging sources: wave w stages K-frag w (16 keys x d) and V-frag 4+w
  // (16 d x 32 keys); per-iteration steps 2048 / 64 shorts.
  const short* gK = Kb + (size_t)(w * 16 + col) * 32 + g8;
  const short* gV = Vb + (size_t)((w & 1) * 16 + col) * 1024 + (w >> 1) * 32 + g8;

  short8 stgK = *(const short8*)gK;            // iter-0 frags (in flight)
  short8 stgV = *(const short8*)gV;

  // Q as B-operand fragment (Q^T[k=d][n=q]); 16B contiguous
  short8 b_q = *(const short8*)(Qb + (q0 + col) * 32 + g8);

  // Build G tables transposed: D[m=16t+grp*4+r][q=col] -> G[q][m]
  {
    const float* rels[2] = {relh_g, relw_g};
#pragma unroll
    for (int tb = 0; tb < 2; ++tb) {
      const float* relg = rels[tb];
#pragma unroll
      for (int t = 0; t < 4; ++t) {
        int m = 16 * t + col;
        int mc = m > 62 ? 62 : m;            // m=63 junk, never read
        const float* rp = relg + mc * 32 + g8;
        float4 f0 = *(const float4*)rp;
        float4 f1 = *(const float4*)(rp + 4);
        short8 ar;
        ar[0] = f2bs(f0.x); ar[1] = f2bs(f0.y);
        ar[2] = f2bs(f0.z); ar[3] = f2bs(f0.w);
        ar[4] = f2bs(f1.x); ar[5] = f2bs(f1.y);
        ar[6] = f2bs(f1.z); ar[7] = f2bs(f1.w);
        f32x4 d = __builtin_amdgcn_mfma_f32_16x16x32_bf16(
            ar, b_q, (f32x4){0.f, 0.f, 0.f, 0.f}, 0, 0, 0);
        short4v o;
        o[0] = f2bs(d[0]); o[1] = f2bs(d[1]);
        o[2] = f2bs(d[2]); o[3] = f2bs(d[3]);
        short* Gd = tb ? Gw_w : &Gh_s[w][0][0];
        *(short4v*)(Gd + col * 68 + 16 * t + grp * 4) = o;
      }
    }
  }
  __asm__ volatile("s_waitcnt lgkmcnt(0)" ::: "memory");

  // Per-lane Gw values are iteration-independent: kx = t*16+grp*4+r.
  float gw[8];
#pragma unroll
  for (int t = 0; t < 2; ++t)
#pragma unroll
    for (int r = 0; r < 4; ++r)
      gw[t * 4 + r] =
          bs2f(Gw_w[col * 68 + t * 16 + grp * 4 + r - j0 - col + 31]);

  const short8 a_one = {0x3F80, 0x3F80, 0x3F80, 0x3F80,
                        0x3F80, 0x3F80, 0x3F80, 0x3F80};

  f32x4 acc0 = {0.f, 0.f, 0.f, 0.f};   // O^T d = grp*4+r,     q = col
  f32x4 acc1 = {0.f, 0.f, 0.f, 0.f};   // O^T d = 16+grp*4+r
  f32x4 accl = {0.f, 0.f, 0.f, 0.f};   // l[q=col] in every reg

  short8 cvA0p = {}, cvA1p = {}, cvB0p = {}, cvB1p = {};  // carried V frags

  // commit iter-0 stage, make visible to all waves (drains gw reads too)
  *(short8*)&kvb[0][w][lane * 8] = stgK;
  *(short8*)&kvb[0][4 + w][lane * 8] = stgV;
  __syncthreads();

#pragma unroll 2
  for (int it = 0; it < 16; ++it) {
    const int cur = it & 1;
    if (it < 15) {
      stgK = *(const short8*)(gK + (size_t)(it + 1) * 2048);
      stgV = *(const short8*)(gV + (size_t)(it + 1) * 64);
    }
    // 8 lane-linear conflict-free b128 reads
    short8 ck0  = *(const short8*)&kvb[cur][0][lane * 8];
    short8 ck1  = *(const short8*)&kvb[cur][1][lane * 8];
    short8 ck2  = *(const short8*)&kvb[cur][2][lane * 8];
    short8 ck3  = *(const short8*)&kvb[cur][3][lane * 8];
    short8 cva0 = *(const short8*)&kvb[cur][4][lane * 8];
    short8 cva1 = *(const short8*)&kvb[cur][5][lane * 8];
    short8 cvb0 = *(const short8*)&kvb[cur][6][lane * 8];
    short8 cvb1 = *(const short8*)&kvb[cur][7][lane * 8];

    // S^T[key][q] for 4 key-groups of 16
    f32x4 s0 = __builtin_amdgcn_mfma_f32_16x16x32_bf16(
        ck0, b_q, (f32x4){0.f, 0.f, 0.f, 0.f}, 0, 0, 0);
    f32x4 s1 = __builtin_amdgcn_mfma_f32_16x16x32_bf16(
        ck1, b_q, (f32x4){0.f, 0.f, 0.f, 0.f}, 0, 0, 0);
    f32x4 s2 = __builtin_amdgcn_mfma_f32_16x16x32_bf16(
        ck2, b_q, (f32x4){0.f, 0.f, 0.f, 0.f}, 0, 0, 0);
    f32x4 s3 = __builtin_amdgcn_mfma_f32_16x16x32_bf16(
        ck3, b_q, (f32x4){0.f, 0.f, 0.f, 0.f}, 0, 0, 0);

    // PV of previous iteration (P writes drained by the last barrier)
    if (it > 0) {
      short8 pA = *(const short8*)&Pt_s[w][cur ^ 1][0][col][g8];
      short8 pB = *(const short8*)&Pt_s[w][cur ^ 1][1][col][g8];
      acc0 = __builtin_amdgcn_mfma_f32_16x16x32_bf16(cvA0p, pA, acc0, 0, 0, 0);
      acc0 = __builtin_amdgcn_mfma_f32_16x16x32_bf16(cvB0p, pB, acc0, 0, 0, 0);
      acc1 = __builtin_amdgcn_mfma_f32_16x16x32_bf16(cvA1p, pA, acc1, 0, 0, 0);
      acc1 = __builtin_amdgcn_mfma_f32_16x16x32_bf16(cvB1p, pB, acc1, 0, 0, 0);
      accl = __builtin_amdgcn_mfma_f32_16x16x32_bf16(a_one, pA, accl, 0, 0, 0);
      accl = __builtin_amdgcn_mfma_f32_16x16x32_bf16(a_one, pB, accl, 0, 0, 0);
    }

    // softmax numerator for the two 32-key chunks of this iteration
    float ghA = bs2f(Gh_s[w][col][2 * it - i + 31]);
    float ghB = bs2f(Gh_s[w][col][2 * it + 1 - i + 31]);
    short4v p0, p1, p2, p3;
#pragma unroll
    for (int r = 0; r < 4; ++r) p0[r] = f2bs(__expf(s0[r] + ghA + gw[r]));
#pragma unroll
    for (int r = 0; r < 4; ++r) p1[r] = f2bs(__expf(s1[r] + ghA + gw[4 + r]));
#pragma unroll
    for (int r = 0; r < 4; ++r) p2[r] = f2bs(__expf(s2[r] + ghB + gw[r]));
#pragma unroll
    for (int r = 0; r < 4; ++r) p3[r] = f2bs(__expf(s3[r] + ghB + gw[4 + r]));
    *(short4v*)&Pt_s[w][cur][0][col][grp * 4] = p0;
    *(short4v*)&Pt_s[w][cur][0][col][16 + grp * 4] = p1;
    *(short4v*)&Pt_s[w][cur][1][col][grp * 4] = p2;
    *(short4v*)&Pt_s[w][cur][1][col][16 + grp * 4] = p3;

    if (it < 15) {
      *(short8*)&kvb[cur ^ 1][w][lane * 8] = stgK;
      *(short8*)&kvb[cur ^ 1][4 + w][lane * 8] = stgV;
    }
    cvA0p = cva0; cvA1p = cva1; cvB0p = cvb0; cvB1p = cvb1;
    __syncthreads();   // everyone done with kvb[cur]; next slot staged
  }

  // drain: PV of the last iteration (P in slot 1)
  {
    short8 pA = *(const short8*)&Pt_s[w][1][0][col][g8];
    short8 pB = *(const short8*)&Pt_s[w][1][1][col][g8];
    acc0 = __builtin_amdgcn_mfma_f32_16x16x32_bf16(cvA0p, pA, acc0, 0, 0, 0);
    acc0 = __builtin_amdgcn_mfma_f32_16x16x32_bf16(cvB0p, pB, acc0, 0, 0, 0);
    acc1 = __builtin_amdgcn_mfma_f32_16x16x32_bf16(cvA1p, pA, acc1, 0, 0, 0);
    acc1 = __builtin_amdgcn_mfma_f32_16x16x32_bf16(cvB1p, pB, acc1, 0, 0, 0);
    accl = __builtin_amdgcn_mfma_f32_16x16x32_bf16(a_one, pA, accl, 0, 0, 0);
    accl = __builtin_amdgcn_mfma_f32_16x16x32_bf16(a_one, pB, accl, 0, 0, 0);
  }

  // epilogue: all-ones A => every accl reg holds l[q=col].
  // Write bf16 amt[b][q][256] with channel = nh*32 + d.
  float rn = 1.0f / accl[0];
  const int bq = bnh >> 3, nh = bnh & 7;
  short* amb = amt + ((size_t)bq * 1024 + q0 + col) * 256 + nh * 32;
  short4v o4a, o4b;
#pragma unroll
  for (int r = 0; r < 4; ++r) {
    o4a[r] = f2bs(acc0[r] * rn);
    o4b[r] = f2bs(acc1[r] * rn);
  }
  *(short4v*)&amb[grp * 4] = o4a;
  *(short4v*)&amb[16 + grp * 4] = o4b;
}

// ---------------------------------------------------------------------------
// Kernel 3 (v2): output projection as bf16 MFMA GEMM, fp32 out channels
// [256,512).  grid (16, 2, 8), block 256 (unchanged).
// ---------------------------------------------------------------------------
__global__ __launch_bounds__(256) void proj_mfma(
    const short* __restrict__ Wa, const short* __restrict__ amt,
    const float* __restrict__ bias, float* __restrict__ out) {
  const int tid = threadIdx.x;
  const int w = tid >> 6, lane = tid & 63;
  const int col = lane & 15, grp = lane >> 4, g8 = grp * 8;
  const int b = blockIdx.z;
  const int p0 = blockIdx.x * 64;
  const int og = blockIdx.y * 128;
  const int ob = og + w * 16;

  const short* wa0 = Wa + (size_t)(ob + col) * 256 + g8;
  const short* wa1 = wa0 + (size_t)64 * 256;
  const short* xp0 = amt + ((size_t)b * 1024 + p0 + col) * 256 + g8;
  const short* xp1 = xp0 + (size_t)16 * 256;
  const short* xp2 = xp0 + (size_t)32 * 256;
  const short* xp3 = xp0 + (size_t)48 * 256;

  f32x4 acc[2][4] = {};
#pragma unroll
  for (int c8 = 0; c8 < 8; ++c8) {
    const int chb = c8 * 32;
    short8 a0 = *(const short8*)(wa0 + chb);
    short8 a1 = *(const short8*)(wa1 + chb);
    short8 b0 = *(const short8*)(xp0 + chb);
    short8 b1 = *(const short8*)(xp1 + chb);
    short8 b2 = *(const short8*)(xp2 + chb);
    short8 b3 = *(const short8*)(xp3 + chb);
    acc[0][0] = __builtin_amdgcn_mfma_f32_16x16x32_bf16(a0, b0, acc[0][0], 0, 0, 0);
    acc[0][1] = __builtin_amdgcn_mfma_f32_16x16x32_bf16(a0, b1, acc[0][1], 0, 0, 0);
    acc[0][2] = __builtin_amdgcn_mfma_f32_16x16x32_bf16(a0, b2, acc[0][2], 0, 0, 0);
    acc[0][3] = __builtin_amdgcn_mfma_f32_16x16x32_bf16(a0, b3, acc[0][3], 0, 0, 0);
    acc[1][0] = __builtin_amdgcn_mfma_f32_16x16x32_bf16(a1, b0, acc[1][0], 0, 0, 0);
    acc[1][1] = __builtin_amdgcn_mfma_f32_16x16x32_bf16(a1, b1, acc[1][1], 0, 0, 0);
    acc[1][2] = __builtin_amdgcn_mfma_f32_16x16x32_bf16(a1, b2, acc[1][2], 0, 0, 0);
    acc[1][3] = __builtin_amdgcn_mfma_f32_16x16x32_bf16(a1, b3, acc[1][3], 0, 0, 0);
  }

#pragma unroll
  for (int j = 0; j < 2; ++j) {
    const int obase = ob + j * 64 + grp * 4;   // + r gives o in [0,256)
    float bv[4];
#pragma unroll
    for (int r = 0; r < 4; ++r) bv[r] = bias[obase + r];
#pragma unroll
    for (int pp = 0; pp < 4; ++pp) {
      const int p = p0 + pp * 16 + col;
#pragma unroll
      for (int r = 0; r < 4; ++r)
        out[((size_t)b * 512 + 256 + obase + r) * 1024 + p] =
            acc[j][pp][r] + bv[r];
    }
  }
}

// ---------------------------------------------------------------------------
// Kernel 4 (v5): LDS-staged MFMA implicit-GEMM 3x3 conv (unchanged).
// grid (32, 2, 8), block 256.
// ---------------------------------------------------------------------------
__global__ __launch_bounds__(256) void conv_mfma(
    const short* __restrict__ xt, const short* __restrict__ Wb,
    const float* __restrict__ bias, float* __restrict__ out) {
  const int tid = threadIdx.x;
  const int w = tid >> 6, lane = tid & 63;
  const int col = lane & 15, grp = lane >> 4, g8 = grp * 8;
  const int r0 = blockIdx.x;            // output row 0..31
  const int oh = blockIdx.y;            // o half 0/1
  const int bb = blockIdx.z;

  __shared__ short xs[3][34][264];      // pitch 264: even bank spread

  {
    const short* src = xt + (((size_t)bb * 34 + r0) * 34) * 256;
    for (int g = tid; g < 3264; g += 256) {       // 3*34*32 8-short groups
      int row = g / 1088;                          // 34*32
      int rem = g - row * 1088;
      int cc = rem >> 5, chg = rem & 31;
      short8 v = *(const short8*)(src + (row * 34 + cc) * 256 + chg * 8);
      *(short8*)&xs[row][cc][chg * 8] = v;
    }
  }
  __syncthreads();

  const int ob0 = oh * 128 + w * 16;    // first o-tile
  const int ob1 = ob0 + 64;             // second o-tile
  const short* Wa0 = Wb + (ob0 + col) * 256 + g8;
  const short* Wa1 = Wb + (ob1 + col) * 256 + g8;

  f32x4 acc00 = {0.f, 0.f, 0.f, 0.f};
  f32x4 acc01 = {0.f, 0.f, 0.f, 0.f};
  f32x4 acc10 = {0.f, 0.f, 0.f, 0.f};
  f32x4 acc11 = {0.f, 0.f, 0.f, 0.f};

#pragma unroll 1
  for (int tap = 0; tap < 9; ++tap) {
    const int u = (tap * 11) >> 5, v = tap - 3 * u;   // exact for tap<9
    const short* wa0 = Wa0 + tap * 65536;
    const short* wa1 = Wa1 + tap * 65536;
    const short* xb0 = &xs[u][col + v][g8];
    const short* xb1 = &xs[u][col + 16 + v][g8];
#pragma unroll
    for (int c8 = 0; c8 < 8; ++c8) {
      const int chb = c8 * 32;
      short8 a0 = *(const short8*)(wa0 + chb);
      short8 a1 = *(const short8*)(wa1 + chb);
      short8 b0 = *(const short8*)(xb0 + chb);
      short8 b1 = *(const short8*)(xb1 + chb);
      acc00 = __builtin_amdgcn_mfma_f32_16x16x32_bf16(a0, b0, acc00, 0, 0, 0);
      acc01 = __builtin_amdgcn_mfma_f32_16x16x32_bf16(a0, b1, acc01, 0, 0, 0);
      acc10 = __builtin_amdgcn_mfma_f32_16x16x32_bf16(a1, b0, acc10, 0, 0, 0);
      acc11 = __builtin_amdgcn_mfma_f32_16x16x32_bf16(a1, b1, acc11, 0, 0, 0);
    }
  }

  float* ob = out + (size_t)bb * 512 * 1024 + r0 * 32;
#pragma unroll
  for (int r = 0; r < 4; ++r) {
    int o0 = ob0 + grp * 4 + r;
    int o1 = ob1 + grp * 4 + r;
    float bv0 = bias[o0], bv1 = bias[o1];
    ob[(size_t)o0 * 1024 + col]      = acc00[r] + bv0;
    ob[(size_t)o0 * 1024 + 16 + col] = acc01[r] + bv0;
    ob[(size_t)o1 * 1024 + col]      = acc10[r] + bv1;
    ob[(size_t)o1 * 1024 + 16 + col] = acc11[r] + bv1;
  }
}

// ---------------------------------------------------------------------------
extern "C" void kernel_launch(void* const* d_in, const int* in_sizes, int n_in,
                              void* d_out, int out_size, void* d_ws, size_t ws_size,
                              hipStream_t stream) {
  const float* x      = (const float*)d_in[0];
  const float* w_qkv  = (const float*)d_in[1];
  const float* b_qkv  = (const float*)d_in[2];
  const float* w_attn = (const float*)d_in[3];
  const float* b_attn = (const float*)d_in[4];
  const float* w_out  = (const float*)d_in[5];
  const float* b_out  = (const float*)d_in[6];
  const float* relw   = (const float*)d_in[7];
  const float* relh   = (const float*)d_in[8];
  float* out = (float*)d_out;

  // ws layout (bytes):
  //   qsb bf16 4MB @0 | ksb 4MB @4M | vtb 4MB @8M | amt bf16 4MB @12M
  //   xt bf16 ~4.52MB @16M | xb2 bf16 4MB @21M
  //   Wq bf16 384KB @25M | Wa bf16 128KB @25.5M | Wb bf16 1.125MB @26M
  // Total ~27.2MB.
  short* qsb = (short*)d_ws;
  short* ksb = qsb + (size_t)2 * 1024 * 1024;
  short* vtb = ksb + (size_t)2 * 1024 * 1024;
  short* amt = (short*)((char*)d_ws + (size_t)12 * 1024 * 1024);
  short* xt  = (short*)((char*)d_ws + (size_t)16 * 1024 * 1024);
  short* xb2 = (short*)((char*)d_ws + (size_t)21 * 1024 * 1024);
  short* Wq  = (short*)((char*)d_ws + (size_t)25 * 1024 * 1024);
  short* Wa  = (short*)((char*)d_ws + (size_t)25 * 1024 * 1024 + 512 * 1024);
  short* Wb  = (short*)((char*)d_ws + (size_t)26 * 1024 * 1024);

  xpose<<<dim3(8, 34), 256, 0, stream>>>(x, xt, xb2);
  wpack<<<1280, 256, 0, stream>>>(w_out, Wb, w_qkv, Wq, w_attn, Wa);
  qkv_mfma<<<dim3(16, 6, 8), 256, 0, stream>>>(Wq, xb2, b_qkv, qsb, ksb, vtb);
  attn_mfma<<<dim3(16, 64), 256, 0, stream>>>(qsb, ksb, vtb, relw, relh, amt);
  proj_mfma<<<dim3(16, 2, 8), 256, 0, stream>>>(Wa, amt, b_attn, out);
  conv_mfma<<<dim3(32, 2, 8), 256, 0, stream>>>(xt, Wb, b_out, out);
}

// Round 5
// 169.912 us; speedup vs baseline: 1.0159x; 1.0159x over previous
//
#include <hip/hip_runtime.h>
#include <hip/hip_bf16.h>

// Round-2 finding: ALL inputs and the output are FP32.
// Round-14: qkv/proj converted to bf16 MFMA GEMMs (-33us).
// Round-15/16: coalesced xpose/wpack; fragment-tiled xb2 (-17us).
// Round-17: attn pipelined (64-key iters, deferred PV) -- NEUTRAL: LDS grew
//   to 45.6KB -> 3 blocks/CU, 1024-block grid needs 4/CU; per-block win
//   (~0.8x) eaten by the 1.33-round dispatch tail (1.33*0.8 ~= 1.07).
// Round-18 (this): restore 4 blocks/CU.  Pt_s is WAVE-PRIVATE (same wave
//   writes and reads it; same-wave LDS ops to aliasing addresses are
//   program-ordered), so the P double-buffer was unnecessary: drop the slot
//   dim (20.5K -> 10.2K), LDS 45.6K -> 35.3K, launch_bounds(256,4).

typedef __hip_bfloat16 bf16;
using short8 = __attribute__((ext_vector_type(8))) short;
using short4v = __attribute__((ext_vector_type(4))) short;
using f32x4 = __attribute__((ext_vector_type(4))) float;

__device__ __forceinline__ short f2bs(float f) {
  union { bf16 b; short s; } u; u.b = __float2bfloat16(f); return u.s;
}
__device__ __forceinline__ float bs2f(short s) {
  union { unsigned u; float f; } x; x.u = ((unsigned)(unsigned short)s) << 16;
  return x.f;
}

// ---------------------------------------------------------------------------
// Prepass A (v4): LDS-transpose repack.
//   xt[b][34][34][256] bf16: spatial-major channel-contig with zero halo.
//   xb2[b][pb][c8][grp][pcol][8] bf16: MFMA-fragment-tiled.
// grid (8, 34), block 256.
// ---------------------------------------------------------------------------
__global__ __launch_bounds__(256) void xpose(
    const float* __restrict__ X, short* __restrict__ xt,
    short* __restrict__ xb2) {
  const int b = blockIdx.x, r = blockIdx.y;   // r in 0..33 (halo coords)
  const int tid = threadIdx.x;
  if (r == 0 || r == 33) {                    // full zero halo row
    short8 z = {};
    short* dst = xt + (((size_t)b * 34 + r) * 34) * 256;
    for (int g = tid; g < 1088; g += 256) *(short8*)(dst + g * 8) = z;
    return;
  }
  __shared__ short xls[32][264];              // [p][c], pitch 264
  {
    const float* src = X + (size_t)b * 256 * 1024 + (r - 1) * 32;
    for (int it = 0; it < 8; ++it) {
      int idx = it * 256 + tid;
      int c = idx >> 3, pq = idx & 7;
      float4 f4 = *(const float4*)(src + (size_t)c * 1024 + pq * 4);
      xls[pq * 4 + 0][c] = f2bs(f4.x);
      xls[pq * 4 + 1][c] = f2bs(f4.y);
      xls[pq * 4 + 2][c] = f2bs(f4.z);
      xls[pq * 4 + 3][c] = f2bs(f4.w);
    }
  }
  __syncthreads();
  {
    short* dst = xt + (((size_t)b * 34 + r) * 34) * 256;
    for (int it = 0; it < 4; ++it) {
      int idx = it * 256 + tid;
      int cc = idx >> 5, co = idx & 31;
      short8 v = *(const short8*)&xls[cc][co * 8];
      *(short8*)(dst + (cc + 1) * 256 + co * 8) = v;
    }
    if (tid < 64) {
      short8 z = {};
      int cce = (tid >> 5) * 33, co = tid & 31;
      *(short8*)(dst + cce * 256 + co * 8) = z;
    }
  }
  {
    short* dst = xb2 + (((size_t)b * 64 + (r - 1) * 2) * 8) * 512;
    for (int it = 0; it < 4; ++it) {
      int g = it * 256 + tid;
      int half = g >> 9, c8 = (g >> 6) & 7, grp = (g >> 4) & 3, pcol = g & 15;
      short8 v = *(const short8*)&xls[half * 16 + pcol][c8 * 32 + grp * 8];
      *(short8*)(dst + ((half * 8 + c8) * 64 + grp * 16 + pcol) * 8) = v;
    }
  }
}

// ---------------------------------------------------------------------------
// Prepass B (v2): coalesced weight packs.  grid 1280, block 256.
// ---------------------------------------------------------------------------
__global__ __launch_bounds__(256) void wpack(
    const float* __restrict__ Wc, short* __restrict__ Wb,
    const float* __restrict__ wq, short* __restrict__ Wq,
    const float* __restrict__ wa, short* __restrict__ Wa) {
  const int bid = blockIdx.x;
  const int tid = threadIdx.x;
  if (bid < 256) {
    __shared__ float ws[2304];                 // one o's [c][tap] block
    const float* src = Wc + (size_t)bid * 2304;
    for (int it = 0; it < 9; ++it) ws[it * 256 + tid] = src[it * 256 + tid];
    __syncthreads();
#pragma unroll
    for (int tap = 0; tap < 9; ++tap)          // bank-free: 9 coprime 32
      Wb[tap * 65536 + bid * 256 + tid] = f2bs(ws[tid * 9 + tap]);
  } else if (bid < 1024) {
    int idx = (bid - 256) * 256 + tid;
    Wq[idx] = f2bs(wq[idx]);
  } else {
    int idx = (bid - 1024) * 256 + tid;
    Wa[idx] = f2bs(wa[idx]);
  }
}

// ---------------------------------------------------------------------------
// Kernel 1 (v9): QKV 1x1 conv as bf16 MFMA GEMM (unchanged this round).
// grid (16, 6, 8), block 256.
// ---------------------------------------------------------------------------
__global__ __launch_bounds__(256) void qkv_mfma(
    const short* __restrict__ Wq, const short* __restrict__ xb2,
    const float* __restrict__ bias,
    short* __restrict__ qsb, short* __restrict__ ksb, short* __restrict__ vtb) {
  const int tid = threadIdx.x;
  const int w = tid >> 6, lane = tid & 63;
  const int col = lane & 15, grp = lane >> 4, g8 = grp * 8;
  const int b = blockIdx.z;
  const int p0 = blockIdx.x * 64;
  const int og = blockIdx.y * 128;
  const int ob = og + w * 16;

  const short* wa0 = Wq + (size_t)(ob + col) * 256 + g8;
  const short* wa1 = wa0 + (size_t)64 * 256;
  const short* xpb = xb2 + (((size_t)b * 64 + blockIdx.x * 4) * 8) * 512 + lane * 8;

  f32x4 acc[2][4] = {};
#pragma unroll
  for (int c8 = 0; c8 < 8; ++c8) {
    const int chb = c8 * 32;
    short8 a0 = *(const short8*)(wa0 + chb);
    short8 a1 = *(const short8*)(wa1 + chb);
    short8 b0 = *(const short8*)(xpb + c8 * 512);
    short8 b1 = *(const short8*)(xpb + 4096 + c8 * 512);
    short8 b2 = *(const short8*)(xpb + 8192 + c8 * 512);
    short8 b3 = *(const short8*)(xpb + 12288 + c8 * 512);
    acc[0][0] = __builtin_amdgcn_mfma_f32_16x16x32_bf16(a0, b0, acc[0][0], 0, 0, 0);
    acc[0][1] = __builtin_amdgcn_mfma_f32_16x16x32_bf16(a0, b1, acc[0][1], 0, 0, 0);
    acc[0][2] = __builtin_amdgcn_mfma_f32_16x16x32_bf16(a0, b2, acc[0][2], 0, 0, 0);
    acc[0][3] = __builtin_amdgcn_mfma_f32_16x16x32_bf16(a0, b3, acc[0][3], 0, 0, 0);
    acc[1][0] = __builtin_amdgcn_mfma_f32_16x16x32_bf16(a1, b0, acc[1][0], 0, 0, 0);
    acc[1][1] = __builtin_amdgcn_mfma_f32_16x16x32_bf16(a1, b1, acc[1][1], 0, 0, 0);
    acc[1][2] = __builtin_amdgcn_mfma_f32_16x16x32_bf16(a1, b2, acc[1][2], 0, 0, 0);
    acc[1][3] = __builtin_amdgcn_mfma_f32_16x16x32_bf16(a1, b3, acc[1][3], 0, 0, 0);
  }

  const float qscale = 0.17677669529663687f;  // 32^-0.5
#pragma unroll
  for (int j = 0; j < 2; ++j) {
    const int obase = ob + j * 64 + grp * 4;   // + r gives the output chan
    const int sect = obase >> 8;               // 0=q 1=k 2=v (tile-uniform)
    const int nh = (obase >> 5) & 7;
    const int d0 = obase & 31;                 // d0..d0+3 consecutive
    const size_t hb = ((size_t)(b * 8 + nh)) * 1024;
    float bv[4];
#pragma unroll
    for (int r = 0; r < 4; ++r) bv[r] = bias[obase + r];
    if (sect == 0) {
#pragma unroll
      for (int pp = 0; pp < 4; ++pp) {
        const int p = p0 + pp * 16 + col;
        short4v o4;
#pragma unroll
        for (int r = 0; r < 4; ++r)
          o4[r] = f2bs((acc[j][pp][r] + bv[r]) * qscale);
        *(short4v*)&qsb[(hb + p) * 32 + d0] = o4;
      }
    } else if (sect == 1) {
#pragma unroll
      for (int pp = 0; pp < 4; ++pp) {
        const int p = p0 + pp * 16 + col;
        short4v o4;
#pragma unroll
        for (int r = 0; r < 4; ++r)
          o4[r] = f2bs(acc[j][pp][r] + bv[r]);
        *(short4v*)&ksb[(hb + p) * 32 + d0] = o4;
      }
    } else {
#pragma unroll
      for (int pp = 0; pp < 4; ++pp) {
        const int p = p0 + pp * 16 + col;
#pragma unroll
        for (int r = 0; r < 4; ++r)
          vtb[hb * 32 + (size_t)(d0 + r) * 1024 + p] = f2bs(acc[j][pp][r] + bv[r]);
      }
    }
  }
}

// ---------------------------------------------------------------------------
// Kernel 2 (v9): pipelined transposed MFMA flash attention, 4 blocks/CU.
// grid (16, 64), block 256 = 4 waves; 1 wave = 16 q x 1024 keys.
// Per 64-key iteration: wave w stages K-frag w + V-frag 4+w into kvb[next];
// all waves read 8 frags lane-linear; QK(t) alongside PV(t-1); P is
// wave-private and single-buffered (same-wave LDS ops are program-ordered).
// LDS: Gh 8704 + kvb 16384 + Pt 10240 = 35328B -> 4 blocks/CU.
// ---------------------------------------------------------------------------
__global__ __launch_bounds__(256, 4) void attn_mfma(
    const short* __restrict__ qsb, const short* __restrict__ ksb,
    const short* __restrict__ vtb,
    const float* __restrict__ relw_g, const float* __restrict__ relh_g,
    short* __restrict__ amt) {
  const int tid = threadIdx.x;
  const int w = tid >> 6, lane = tid & 63;
  const int col = lane & 15, grp = lane >> 4, g8 = grp * 8;
  const int qt = blockIdx.x * 4 + w;       // q-tile 0..63
  const int bnh = blockIdx.y;
  const int q0 = qt * 16;
  const int i = qt >> 1;                   // query row, constant per wave
  const int j0 = (qt & 1) * 16;            // query col base

  const short* Qb = qsb + (size_t)bnh * 32768;
  const short* Kb = ksb + (size_t)bnh * 32768;
  const short* Vb = vtb + (size_t)bnh * 32768;

  __shared__ short Gh_s[4][16][68];     // [wave][q][m]        8704B
  __shared__ short kvb[2][8][512];      // [slot][frag][...]  16384B
  __shared__ short Pt_s[4][2][16][40];  // [wave][half][q][key] 10240B
  // Gw scratch aliased over this wave's Pt_s (dead after gw[] preload;
  // wave-private, and the later P-writes are same-wave program-ordered).
  short* Gw_w = &Pt_s[w][0][0][0];      // needs 1083 <= 1280 shorts, ok

  // staging sources: wave w stages K-frag w (16 keys x d) and V-frag 4+w
  // (16 d x 32 keys); per-iteration steps 2048 / 64 shorts.
  const short* gK = Kb + (size_t)(w * 16 + col) * 32 + g8;
  const short* gV = Vb + (size_t)((w & 1) * 16 + col) * 1024 + (w >> 1) * 32 + g8;

  short8 stgK = *(const short8*)gK;            // iter-0 frags (in flight)
  short8 stgV = *(const short8*)gV;

  // Q as B-operand fragment (Q^T[k=d][n=q]); 16B contiguous
  short8 b_q = *(const short8*)(Qb + (q0 + col) * 32 + g8);

  // Build G tables transposed: D[m=16t+grp*4+r][q=col] -> G[q][m]
  {
    const float* rels[2] = {relh_g, relw_g};
#pragma unroll
    for (int tb = 0; tb < 2; ++tb) {
      const float* relg = rels[tb];
#pragma unroll
      for (int t = 0; t < 4; ++t) {
        int m = 16 * t + col;
        int mc = m > 62 ? 62 : m;            // m=63 junk, never read
        const float* rp = relg + mc * 32 + g8;
        float4 f0 = *(const float4*)rp;
        float4 f1 = *(const float4*)(rp + 4);
        short8 ar;
        ar[0] = f2bs(f0.x); ar[1] = f2bs(f0.y);
        ar[2] = f2bs(f0.z); ar[3] = f2bs(f0.w);
        ar[4] = f2bs(f1.x); ar[5] = f2bs(f1.y);
        ar[6] = f2bs(f1.z); ar[7] = f2bs(f1.w);
        f32x4 d = __builtin_amdgcn_mfma_f32_16x16x32_bf16(
            ar, b_q, (f32x4){0.f, 0.f, 0.f, 0.f}, 0, 0, 0);
        short4v o;
        o[0] = f2bs(d[0]); o[1] = f2bs(d[1]);
        o[2] = f2bs(d[2]); o[3] = f2bs(d[3]);
        short* Gd = tb ? Gw_w : &Gh_s[w][0][0];
        *(short4v*)(Gd + col * 68 + 16 * t + grp * 4) = o;
      }
    }
  }
  __asm__ volatile("s_waitcnt lgkmcnt(0)" ::: "memory");

  // Per-lane Gw values are iteration-independent: kx = t*16+grp*4+r.
  float gw[8];
#pragma unroll
  for (int t = 0; t < 2; ++t)
#pragma unroll
    for (int r = 0; r < 4; ++r)
      gw[t * 4 + r] =
          bs2f(Gw_w[col * 68 + t * 16 + grp * 4 + r - j0 - col + 31]);

  const short8 a_one = {0x3F80, 0x3F80, 0x3F80, 0x3F80,
                        0x3F80, 0x3F80, 0x3F80, 0x3F80};

  f32x4 acc0 = {0.f, 0.f, 0.f, 0.f};   // O^T d = grp*4+r,     q = col
  f32x4 acc1 = {0.f, 0.f, 0.f, 0.f};   // O^T d = 16+grp*4+r
  f32x4 accl = {0.f, 0.f, 0.f, 0.f};   // l[q=col] in every reg

  short8 cvA0p = {}, cvA1p = {}, cvB0p = {}, cvB1p = {};  // carried V frags

  // commit iter-0 stage, make visible to all waves (drains gw reads too)
  *(short8*)&kvb[0][w][lane * 8] = stgK;
  *(short8*)&kvb[0][4 + w][lane * 8] = stgV;
  __syncthreads();

#pragma unroll 2
  for (int it = 0; it < 16; ++it) {
    const int cur = it & 1;
    if (it < 15) {
      stgK = *(const short8*)(gK + (size_t)(it + 1) * 2048);
      stgV = *(const short8*)(gV + (size_t)(it + 1) * 64);
    }
    // 8 lane-linear conflict-free b128 reads
    short8 ck0  = *(const short8*)&kvb[cur][0][lane * 8];
    short8 ck1  = *(const short8*)&kvb[cur][1][lane * 8];
    short8 ck2  = *(const short8*)&kvb[cur][2][lane * 8];
    short8 ck3  = *(const short8*)&kvb[cur][3][lane * 8];
    short8 cva0 = *(const short8*)&kvb[cur][4][lane * 8];
    short8 cva1 = *(const short8*)&kvb[cur][5][lane * 8];
    short8 cvb0 = *(const short8*)&kvb[cur][6][lane * 8];
    short8 cvb1 = *(const short8*)&kvb[cur][7][lane * 8];

    // S^T[key][q] for 4 key-groups of 16
    f32x4 s0 = __builtin_amdgcn_mfma_f32_16x16x32_bf16(
        ck0, b_q, (f32x4){0.f, 0.f, 0.f, 0.f}, 0, 0, 0);
    f32x4 s1 = __builtin_amdgcn_mfma_f32_16x16x32_bf16(
        ck1, b_q, (f32x4){0.f, 0.f, 0.f, 0.f}, 0, 0, 0);
    f32x4 s2 = __builtin_amdgcn_mfma_f32_16x16x32_bf16(
        ck2, b_q, (f32x4){0.f, 0.f, 0.f, 0.f}, 0, 0, 0);
    f32x4 s3 = __builtin_amdgcn_mfma_f32_16x16x32_bf16(
        ck3, b_q, (f32x4){0.f, 0.f, 0.f, 0.f}, 0, 0, 0);

    // PV of previous iteration (P single-buffered, wave-private: these
    // ds_reads precede this iteration's P ds_writes in program order)
    if (it > 0) {
      short8 pA = *(const short8*)&Pt_s[w][0][col][g8];
      short8 pB = *(const short8*)&Pt_s[w][1][col][g8];
      acc0 = __builtin_amdgcn_mfma_f32_16x16x32_bf16(cvA0p, pA, acc0, 0, 0, 0);
      acc0 = __builtin_amdgcn_mfma_f32_16x16x32_bf16(cvB0p, pB, acc0, 0, 0, 0);
      acc1 = __builtin_amdgcn_mfma_f32_16x16x32_bf16(cvA1p, pA, acc1, 0, 0, 0);
      acc1 = __builtin_amdgcn_mfma_f32_16x16x32_bf16(cvB1p, pB, acc1, 0, 0, 0);
      accl = __builtin_amdgcn_mfma_f32_16x16x32_bf16(a_one, pA, accl, 0, 0, 0);
      accl = __builtin_amdgcn_mfma_f32_16x16x32_bf16(a_one, pB, accl, 0, 0, 0);
    }

    // softmax numerator for the two 32-key chunks of this iteration
    float ghA = bs2f(Gh_s[w][col][2 * it - i + 31]);
    float ghB = bs2f(Gh_s[w][col][2 * it + 1 - i + 31]);
    short4v p0, p1, p2, p3;
#pragma unroll
    for (int r = 0; r < 4; ++r) p0[r] = f2bs(__expf(s0[r] + ghA + gw[r]));
#pragma unroll
    for (int r = 0; r < 4; ++r) p1[r] = f2bs(__expf(s1[r] + ghA + gw[4 + r]));
#pragma unroll
    for (int r = 0; r < 4; ++r) p2[r] = f2bs(__expf(s2[r] + ghB + gw[r]));
#pragma unroll
    for (int r = 0; r < 4; ++r) p3[r] = f2bs(__expf(s3[r] + ghB + gw[4 + r]));
    *(short4v*)&Pt_s[w][0][col][grp * 4] = p0;
    *(short4v*)&Pt_s[w][0][col][16 + grp * 4] = p1;
    *(short4v*)&Pt_s[w][1][col][grp * 4] = p2;
    *(short4v*)&Pt_s[w][1][col][16 + grp * 4] = p3;

    if (it < 15) {
      *(short8*)&kvb[cur ^ 1][w][lane * 8] = stgK;
      *(short8*)&kvb[cur ^ 1][4 + w][lane * 8] = stgV;
    }
    cvA0p = cva0; cvA1p = cva1; cvB0p = cvb0; cvB1p = cvb1;
    __syncthreads();   // everyone done with kvb[cur]; next slot staged
  }

  // drain: PV of the last iteration
  {
    short8 pA = *(const short8*)&Pt_s[w][0][col][g8];
    short8 pB = *(const short8*)&Pt_s[w][1][col][g8];
    acc0 = __builtin_amdgcn_mfma_f32_16x16x32_bf16(cvA0p, pA, acc0, 0, 0, 0);
    acc0 = __builtin_amdgcn_mfma_f32_16x16x32_bf16(cvB0p, pB, acc0, 0, 0, 0);
    acc1 = __builtin_amdgcn_mfma_f32_16x16x32_bf16(cvA1p, pA, acc1, 0, 0, 0);
    acc1 = __builtin_amdgcn_mfma_f32_16x16x32_bf16(cvB1p, pB, acc1, 0, 0, 0);
    accl = __builtin_amdgcn_mfma_f32_16x16x32_bf16(a_one, pA, accl, 0, 0, 0);
    accl = __builtin_amdgcn_mfma_f32_16x16x32_bf16(a_one, pB, accl, 0, 0, 0);
  }

  // epilogue: all-ones A => every accl reg holds l[q=col].
  // Write bf16 amt[b][q][256] with channel = nh*32 + d.
  float rn = 1.0f / accl[0];
  const int bq = bnh >> 3, nh = bnh & 7;
  short* amb = amt + ((size_t)bq * 1024 + q0 + col) * 256 + nh * 32;
  short4v o4a, o4b;
#pragma unroll
  for (int r = 0; r < 4; ++r) {
    o4a[r] = f2bs(acc0[r] * rn);
    o4b[r] = f2bs(acc1[r] * rn);
  }
  *(short4v*)&amb[grp * 4] = o4a;
  *(short4v*)&amb[16 + grp * 4] = o4b;
}

// ---------------------------------------------------------------------------
// Kernel 3 (v2): output projection as bf16 MFMA GEMM, fp32 out channels
// [256,512).  grid (16, 2, 8), block 256 (unchanged).
// ---------------------------------------------------------------------------
__global__ __launch_bounds__(256) void proj_mfma(
    const short* __restrict__ Wa, const short* __restrict__ amt,
    const float* __restrict__ bias, float* __restrict__ out) {
  const int tid = threadIdx.x;
  const int w = tid >> 6, lane = tid & 63;
  const int col = lane & 15, grp = lane >> 4, g8 = grp * 8;
  const int b = blockIdx.z;
  const int p0 = blockIdx.x * 64;
  const int og = blockIdx.y * 128;
  const int ob = og + w * 16;

  const short* wa0 = Wa + (size_t)(ob + col) * 256 + g8;
  const short* wa1 = wa0 + (size_t)64 * 256;
  const short* xp0 = amt + ((size_t)b * 1024 + p0 + col) * 256 + g8;
  const short* xp1 = xp0 + (size_t)16 * 256;
  const short* xp2 = xp0 + (size_t)32 * 256;
  const short* xp3 = xp0 + (size_t)48 * 256;

  f32x4 acc[2][4] = {};
#pragma unroll
  for (int c8 = 0; c8 < 8; ++c8) {
    const int chb = c8 * 32;
    short8 a0 = *(const short8*)(wa0 + chb);
    short8 a1 = *(const short8*)(wa1 + chb);
    short8 b0 = *(const short8*)(xp0 + chb);
    short8 b1 = *(const short8*)(xp1 + chb);
    short8 b2 = *(const short8*)(xp2 + chb);
    short8 b3 = *(const short8*)(xp3 + chb);
    acc[0][0] = __builtin_amdgcn_mfma_f32_16x16x32_bf16(a0, b0, acc[0][0], 0, 0, 0);
    acc[0][1] = __builtin_amdgcn_mfma_f32_16x16x32_bf16(a0, b1, acc[0][1], 0, 0, 0);
    acc[0][2] = __builtin_amdgcn_mfma_f32_16x16x32_bf16(a0, b2, acc[0][2], 0, 0, 0);
    acc[0][3] = __builtin_amdgcn_mfma_f32_16x16x32_bf16(a0, b3, acc[0][3], 0, 0, 0);
    acc[1][0] = __builtin_amdgcn_mfma_f32_16x16x32_bf16(a1, b0, acc[1][0], 0, 0, 0);
    acc[1][1] = __builtin_amdgcn_mfma_f32_16x16x32_bf16(a1, b1, acc[1][1], 0, 0, 0);
    acc[1][2] = __builtin_amdgcn_mfma_f32_16x16x32_bf16(a1, b2, acc[1][2], 0, 0, 0);
    acc[1][3] = __builtin_amdgcn_mfma_f32_16x16x32_bf16(a1, b3, acc[1][3], 0, 0, 0);
  }

#pragma unroll
  for (int j = 0; j < 2; ++j) {
    const int obase = ob + j * 64 + grp * 4;   // + r gives o in [0,256)
    float bv[4];
#pragma unroll
    for (int r = 0; r < 4; ++r) bv[r] = bias[obase + r];
#pragma unroll
    for (int pp = 0; pp < 4; ++pp) {
      const int p = p0 + pp * 16 + col;
#pragma unroll
      for (int r = 0; r < 4; ++r)
        out[((size_t)b * 512 + 256 + obase + r) * 1024 + p] =
            acc[j][pp][r] + bv[r];
    }
  }
}

// ---------------------------------------------------------------------------
// Kernel 4 (v5): LDS-staged MFMA implicit-GEMM 3x3 conv (unchanged).
// grid (32, 2, 8), block 256.
// ---------------------------------------------------------------------------
__global__ __launch_bounds__(256) void conv_mfma(
    const short* __restrict__ xt, const short* __restrict__ Wb,
    const float* __restrict__ bias, float* __restrict__ out) {
  const int tid = threadIdx.x;
  const int w = tid >> 6, lane = tid & 63;
  const int col = lane & 15, grp = lane >> 4, g8 = grp * 8;
  const int r0 = blockIdx.x;            // output row 0..31
  const int oh = blockIdx.y;            // o half 0/1
  const int bb = blockIdx.z;

  __shared__ short xs[3][34][264];      // pitch 264: even bank spread

  {
    const short* src = xt + (((size_t)bb * 34 + r0) * 34) * 256;
    for (int g = tid; g < 3264; g += 256) {       // 3*34*32 8-short groups
      int row = g / 1088;                          // 34*32
      int rem = g - row * 1088;
      int cc = rem >> 5, chg = rem & 31;
      short8 v = *(const short8*)(src + (row * 34 + cc) * 256 + chg * 8);
      *(short8*)&xs[row][cc][chg * 8] = v;
    }
  }
  __syncthreads();

  const int ob0 = oh * 128 + w * 16;    // first o-tile
  const int ob1 = ob0 + 64;             // second o-tile
  const short* Wa0 = Wb + (ob0 + col) * 256 + g8;
  const short* Wa1 = Wb + (ob1 + col) * 256 + g8;

  f32x4 acc00 = {0.f, 0.f, 0.f, 0.f};
  f32x4 acc01 = {0.f, 0.f, 0.f, 0.f};
  f32x4 acc10 = {0.f, 0.f, 0.f, 0.f};
  f32x4 acc11 = {0.f, 0.f, 0.f, 0.f};

#pragma unroll 1
  for (int tap = 0; tap < 9; ++tap) {
    const int u = (tap * 11) >> 5, v = tap - 3 * u;   // exact for tap<9
    const short* wa0 = Wa0 + tap * 65536;
    const short* wa1 = Wa1 + tap * 65536;
    const short* xb0 = &xs[u][col + v][g8];
    const short* xb1 = &xs[u][col + 16 + v][g8];
#pragma unroll
    for (int c8 = 0; c8 < 8; ++c8) {
      const int chb = c8 * 32;
      short8 a0 = *(const short8*)(wa0 + chb);
      short8 a1 = *(const short8*)(wa1 + chb);
      short8 b0 = *(const short8*)(xb0 + chb);
      short8 b1 = *(const short8*)(xb1 + chb);
      acc00 = __builtin_amdgcn_mfma_f32_16x16x32_bf16(a0, b0, acc00, 0, 0, 0);
      acc01 = __builtin_amdgcn_mfma_f32_16x16x32_bf16(a0, b1, acc01, 0, 0, 0);
      acc10 = __builtin_amdgcn_mfma_f32_16x16x32_bf16(a1, b0, acc10, 0, 0, 0);
      acc11 = __builtin_amdgcn_mfma_f32_16x16x32_bf16(a1, b1, acc11, 0, 0, 0);
    }
  }

  float* ob = out + (size_t)bb * 512 * 1024 + r0 * 32;
#pragma unroll
  for (int r = 0; r < 4; ++r) {
    int o0 = ob0 + grp * 4 + r;
    int o1 = ob1 + grp * 4 + r;
    float bv0 = bias[o0], bv1 = bias[o1];
    ob[(size_t)o0 * 1024 + col]      = acc00[r] + bv0;
    ob[(size_t)o0 * 1024 + 16 + col] = acc01[r] + bv0;
    ob[(size_t)o1 * 1024 + col]      = acc10[r] + bv1;
    ob[(size_t)o1 * 1024 + 16 + col] = acc11[r] + bv1;
  }
}

// ---------------------------------------------------------------------------
extern "C" void kernel_launch(void* const* d_in, const int* in_sizes, int n_in,
                              void* d_out, int out_size, void* d_ws, size_t ws_size,
                              hipStream_t stream) {
  const float* x      = (const float*)d_in[0];
  const float* w_qkv  = (const float*)d_in[1];
  const float* b_qkv  = (const float*)d_in[2];
  const float* w_attn = (const float*)d_in[3];
  const float* b_attn = (const float*)d_in[4];
  const float* w_out  = (const float*)d_in[5];
  const float* b_out  = (const float*)d_in[6];
  const float* relw   = (const float*)d_in[7];
  const float* relh   = (const float*)d_in[8];
  float* out = (float*)d_out;

  // ws layout (bytes):
  //   qsb bf16 4MB @0 | ksb 4MB @4M | vtb 4MB @8M | amt bf16 4MB @12M
  //   xt bf16 ~4.52MB @16M | xb2 bf16 4MB @21M
  //   Wq bf16 384KB @25M | Wa bf16 128KB @25.5M | Wb bf16 1.125MB @26M
  // Total ~27.2MB.
  short* qsb = (short*)d_ws;
  short* ksb = qsb + (size_t)2 * 1024 * 1024;
  short* vtb = ksb + (size_t)2 * 1024 * 1024;
  short* amt = (short*)((char*)d_ws + (size_t)12 * 1024 * 1024);
  short* xt  = (short*)((char*)d_ws + (size_t)16 * 1024 * 1024);
  short* xb2 = (short*)((char*)d_ws + (size_t)21 * 1024 * 1024);
  short* Wq  = (short*)((char*)d_ws + (size_t)25 * 1024 * 1024);
  short* Wa  = (short*)((char*)d_ws + (size_t)25 * 1024 * 1024 + 512 * 1024);
  short* Wb  = (short*)((char*)d_ws + (size_t)26 * 1024 * 1024);

  xpose<<<dim3(8, 34), 256, 0, stream>>>(x, xt, xb2);
  wpack<<<1280, 256, 0, stream>>>(w_out, Wb, w_qkv, Wq, w_attn, Wa);
  qkv_mfma<<<dim3(16, 6, 8), 256, 0, stream>>>(Wq, xb2, b_qkv, qsb, ksb, vtb);
  attn_mfma<<<dim3(16, 64), 256, 0, stream>>>(qsb, ksb, vtb, relw, relh, amt);
  proj_mfma<<<dim3(16, 2, 8), 256, 0, stream>>>(Wa, amt, b_attn, out);
  conv_mfma<<<dim3(32, 2, 8), 256, 0, stream>>>(xt, Wb, b_out, out);
}

// Round 6
// 151.863 us; speedup vs baseline: 1.1366x; 1.1189x over previous
//
#include <hip/hip_runtime.h>
#include <hip/hip_bf16.h>

// Round-2 finding: ALL inputs and the output are FP32.
// Round-14: qkv/proj -> bf16 MFMA GEMMs (-33us).
// Round-15/16: coalesced xpose/wpack; fragment-tiled xb2 (-17us).
// Round-17/18: attn pipeline restructure + occupancy fix -- NEUTRAL twice;
//   serialization was not attn's limiter.  No user kernel in top-5 (all
//   <=44us): time is SPREAD.  The one proven win (xb2 tiling) generalizes.
// Round-19 (this): fragment-tile EVERY remaining scattered MFMA operand:
//   Wq2/Wa2/Wb2 (A-operands, were 16B @512B-stride/lane), ksb2/vtb2 (attn
//   staging, were 16x64B gathers), amt2 (proj B, same as xb2 fix).  All
//   consumers now load base + frag*512 + lane*8 = one 1KB transaction.
//   Producer-side address permutations only; values bit-identical.

typedef __hip_bfloat16 bf16;
using short8 = __attribute__((ext_vector_type(8))) short;
using short4v = __attribute__((ext_vector_type(4))) short;
using f32x4 = __attribute__((ext_vector_type(4))) float;

__device__ __forceinline__ short f2bs(float f) {
  union { bf16 b; short s; } u; u.b = __float2bfloat16(f); return u.s;
}
__device__ __forceinline__ float bs2f(short s) {
  union { unsigned u; float f; } x; x.u = ((unsigned)(unsigned short)s) << 16;
  return x.f;
}

// Fragment-tile address for a [O][256] bf16 weight matrix:
// frag (o16 = o>>4, c8 = c>>5), lane (col = o&15, grp = (c>>3)&3), j = c&7.
__device__ __forceinline__ size_t wtile(int o, int c) {
  return ((size_t)((o >> 4) * 8 + (c >> 5)) * 512) +
         (((c >> 3) & 3) * 16 + (o & 15)) * 8 + (c & 7);
}

// ---------------------------------------------------------------------------
// Prepass A (v4): LDS-transpose repack (unchanged).
//   xt[b][34][34][256] bf16 halo layout; xb2 MFMA-fragment-tiled.
// grid (8, 34), block 256.
// ---------------------------------------------------------------------------
__global__ __launch_bounds__(256) void xpose(
    const float* __restrict__ X, short* __restrict__ xt,
    short* __restrict__ xb2) {
  const int b = blockIdx.x, r = blockIdx.y;   // r in 0..33 (halo coords)
  const int tid = threadIdx.x;
  if (r == 0 || r == 33) {                    // full zero halo row
    short8 z = {};
    short* dst = xt + (((size_t)b * 34 + r) * 34) * 256;
    for (int g = tid; g < 1088; g += 256) *(short8*)(dst + g * 8) = z;
    return;
  }
  __shared__ short xls[32][264];              // [p][c], pitch 264
  {
    const float* src = X + (size_t)b * 256 * 1024 + (r - 1) * 32;
    for (int it = 0; it < 8; ++it) {
      int idx = it * 256 + tid;
      int c = idx >> 3, pq = idx & 7;
      float4 f4 = *(const float4*)(src + (size_t)c * 1024 + pq * 4);
      xls[pq * 4 + 0][c] = f2bs(f4.x);
      xls[pq * 4 + 1][c] = f2bs(f4.y);
      xls[pq * 4 + 2][c] = f2bs(f4.z);
      xls[pq * 4 + 3][c] = f2bs(f4.w);
    }
  }
  __syncthreads();
  {
    short* dst = xt + (((size_t)b * 34 + r) * 34) * 256;
    for (int it = 0; it < 4; ++it) {
      int idx = it * 256 + tid;
      int cc = idx >> 5, co = idx & 31;
      short8 v = *(const short8*)&xls[cc][co * 8];
      *(short8*)(dst + (cc + 1) * 256 + co * 8) = v;
    }
    if (tid < 64) {
      short8 z = {};
      int cce = (tid >> 5) * 33, co = tid & 31;
      *(short8*)(dst + cce * 256 + co * 8) = z;
    }
  }
  {
    short* dst = xb2 + (((size_t)b * 64 + (r - 1) * 2) * 8) * 512;
    for (int it = 0; it < 4; ++it) {
      int g = it * 256 + tid;
      int half = g >> 9, c8 = (g >> 6) & 7, grp = (g >> 4) & 3, pcol = g & 15;
      short8 v = *(const short8*)&xls[half * 16 + pcol][c8 * 32 + grp * 8];
      *(short8*)(dst + ((half * 8 + c8) * 64 + grp * 16 + pcol) * 8) = v;
    }
  }
}

// ---------------------------------------------------------------------------
// Prepass B (v3): weight packs, now emitting FRAGMENT-TILED layouts.
//   blocks [0,256):   conv weights -> Wb2[tap][o16][c8][lane][8]
//   blocks [256,1024): Wq2 tiled; blocks [1024,1280): Wa2 tiled.
// grid 1280, block 256.
// ---------------------------------------------------------------------------
__global__ __launch_bounds__(256) void wpack(
    const float* __restrict__ Wc, short* __restrict__ Wb2,
    const float* __restrict__ wq, short* __restrict__ Wq2,
    const float* __restrict__ wa, short* __restrict__ Wa2) {
  const int bid = blockIdx.x;
  const int tid = threadIdx.x;
  if (bid < 256) {
    __shared__ float ws[2304];                 // one o's [c][tap] block
    const float* src = Wc + (size_t)bid * 2304;
    for (int it = 0; it < 9; ++it) ws[it * 256 + tid] = src[it * 256 + tid];
    __syncthreads();
    const int o = bid, c = tid;
#pragma unroll
    for (int tap = 0; tap < 9; ++tap)
      Wb2[(size_t)tap * 65536 + wtile(o, c)] = f2bs(ws[c * 9 + tap]);
  } else if (bid < 1024) {
    const int o = bid - 256, c = tid;
    Wq2[wtile(o, c)] = f2bs(wq[o * 256 + c]);
  } else {
    const int o = bid - 1024, c = tid;
    Wa2[wtile(o, c)] = f2bs(wa[o * 256 + c]);
  }
}

// ---------------------------------------------------------------------------
// Kernel 1 (v10): QKV 1x1 conv as bf16 MFMA GEMM, all operands lane-linear.
// grid (16, 6, 8), block 256.  Epilogue emits:
//   qsb[bnh][q][d] (scaled, unchanged) | ksb2 / vtb2 in kvb-staging layout:
//   [bnh][kit(16)][frag(4)][lane(64)][8].
// ---------------------------------------------------------------------------
__global__ __launch_bounds__(256) void qkv_mfma(
    const short* __restrict__ Wq2, const short* __restrict__ xb2,
    const float* __restrict__ bias,
    short* __restrict__ qsb, short* __restrict__ ksb2, short* __restrict__ vtb2) {
  const int tid = threadIdx.x;
  const int w = tid >> 6, lane = tid & 63;
  const int col = lane & 15, grp = lane >> 4;
  const int b = blockIdx.z;
  const int bx = blockIdx.x;
  const int p0 = bx * 64;
  const int ob = blockIdx.y * 128 + w * 16;
  const int o16 = ob >> 4;                    // = by*8 + w

  const short* wbase = Wq2 + lane * 8;
  const short* xpb = xb2 + (((size_t)b * 64 + bx * 4) * 8) * 512 + lane * 8;

  f32x4 acc[2][4] = {};
#pragma unroll
  for (int c8 = 0; c8 < 8; ++c8) {
    short8 a0 = *(const short8*)(wbase + (size_t)(o16 * 8 + c8) * 512);
    short8 a1 = *(const short8*)(wbase + (size_t)((o16 + 4) * 8 + c8) * 512);
    short8 b0 = *(const short8*)(xpb + c8 * 512);
    short8 b1 = *(const short8*)(xpb + 4096 + c8 * 512);
    short8 b2 = *(const short8*)(xpb + 8192 + c8 * 512);
    short8 b3 = *(const short8*)(xpb + 12288 + c8 * 512);
    acc[0][0] = __builtin_amdgcn_mfma_f32_16x16x32_bf16(a0, b0, acc[0][0], 0, 0, 0);
    acc[0][1] = __builtin_amdgcn_mfma_f32_16x16x32_bf16(a0, b1, acc[0][1], 0, 0, 0);
    acc[0][2] = __builtin_amdgcn_mfma_f32_16x16x32_bf16(a0, b2, acc[0][2], 0, 0, 0);
    acc[0][3] = __builtin_amdgcn_mfma_f32_16x16x32_bf16(a0, b3, acc[0][3], 0, 0, 0);
    acc[1][0] = __builtin_amdgcn_mfma_f32_16x16x32_bf16(a1, b0, acc[1][0], 0, 0, 0);
    acc[1][1] = __builtin_amdgcn_mfma_f32_16x16x32_bf16(a1, b1, acc[1][1], 0, 0, 0);
    acc[1][2] = __builtin_amdgcn_mfma_f32_16x16x32_bf16(a1, b2, acc[1][2], 0, 0, 0);
    acc[1][3] = __builtin_amdgcn_mfma_f32_16x16x32_bf16(a1, b3, acc[1][3], 0, 0, 0);
  }

  const float qscale = 0.17677669529663687f;  // 32^-0.5
#pragma unroll
  for (int j = 0; j < 2; ++j) {
    const int obase = ob + j * 64 + grp * 4;   // + r gives the output chan
    const int sect = obase >> 8;               // 0=q 1=k 2=v (tile-uniform)
    const int nh = (obase >> 5) & 7;
    const int d0 = obase & 31;                 // d0..d0+3 consecutive
    const size_t hb = ((size_t)(b * 8 + nh)) * 1024;    // qsb base
    const size_t hb2 = ((size_t)(b * 8 + nh)) * 32768;  // ksb2/vtb2 base
    float bv[4];
#pragma unroll
    for (int r = 0; r < 4; ++r) bv[r] = bias[obase + r];
    if (sect == 0) {
#pragma unroll
      for (int pp = 0; pp < 4; ++pp) {
        const int p = p0 + pp * 16 + col;
        short4v o4;
#pragma unroll
        for (int r = 0; r < 4; ++r)
          o4[r] = f2bs((acc[j][pp][r] + bv[r]) * qscale);
        *(short4v*)&qsb[(hb + p) * 32 + d0] = o4;
      }
    } else if (sect == 1) {
      // ksb2[bnh][kit=bx][frag=pp][lane'=(grp'=d>>3, col'=key&15)][j'=d&7]
      // d = (w&1)*16 + grp*4 + r -> d>>3 = (w&1)*2 + (grp>>1),
      // d&7 = (grp&1)*4 + r -> 4 consecutive shorts.
      const size_t kb = hb2 + (size_t)bx * 2048 + (w & 1) * 256 +
                        (grp >> 1) * 128 + col * 8 + (grp & 1) * 4;
#pragma unroll
      for (int pp = 0; pp < 4; ++pp) {
        short4v o4;
#pragma unroll
        for (int r = 0; r < 4; ++r)
          o4[r] = f2bs(acc[j][pp][r] + bv[r]);
        *(short4v*)&ksb2[kb + pp * 512] = o4;
      }
    } else {
      // vtb2[bnh][kit=bx][frag=(pp>>1)*2+(w&1)]
      //     [lane'=(grp'=(pp&1)*2+(col>>3), col'=d&15=grp*4+r)][j'=key&7]
      const size_t vb0 = hb2 + (size_t)bx * 2048 + (size_t)(w & 1) * 512 +
                         (col >> 3) * 128 + (grp * 4) * 8 + (col & 7);
#pragma unroll
      for (int pp = 0; pp < 4; ++pp) {
        const size_t vb = vb0 + (pp >> 1) * 1024 + (pp & 1) * 256;
#pragma unroll
        for (int r = 0; r < 4; ++r)
          vtb2[vb + r * 8] = f2bs(acc[j][pp][r] + bv[r]);
      }
    }
  }
}

// ---------------------------------------------------------------------------
// Kernel 2 (v10): pipelined transposed MFMA flash attention; K/V staging
// now lane-linear from ksb2/vtb2 (kvb-layout in global).  Epilogue writes
// amt2 in xb2-style fragment tiling for the projection.
// grid (16, 64), block 256 = 4 waves.  LDS 35.3KB -> 4 blocks/CU.
// ---------------------------------------------------------------------------
__global__ __launch_bounds__(256, 4) void attn_mfma(
    const short* __restrict__ qsb, const short* __restrict__ ksb2,
    const short* __restrict__ vtb2,
    const float* __restrict__ relw_g, const float* __restrict__ relh_g,
    short* __restrict__ amt2) {
  const int tid = threadIdx.x;
  const int w = tid >> 6, lane = tid & 63;
  const int col = lane & 15, grp = lane >> 4, g8 = grp * 8;
  const int qt = blockIdx.x * 4 + w;       // q-tile 0..63
  const int bnh = blockIdx.y;
  const int q0 = qt * 16;
  const int i = qt >> 1;                   // query row, constant per wave
  const int j0 = (qt & 1) * 16;            // query col base

  const short* Qb = qsb + (size_t)bnh * 32768;

  __shared__ short Gh_s[4][16][68];     // [wave][q][m]        8704B
  __shared__ short kvb[2][8][512];      // [slot][frag][...]  16384B
  __shared__ short Pt_s[4][2][16][40];  // [wave][half][q][key] 10240B
  short* Gw_w = &Pt_s[w][0][0][0];      // scratch alias (wave-private)

  // lane-linear staging sources (one 1KB transaction per instruction)
  const short* gK = ksb2 + (size_t)bnh * 32768 + w * 512 + lane * 8;
  const short* gV = vtb2 + (size_t)bnh * 32768 + w * 512 + lane * 8;

  short8 stgK = *(const short8*)gK;            // iter-0 frags (in flight)
  short8 stgV = *(const short8*)gV;

  // Q as B-operand fragment (Q^T[k=d][n=q]); 16B contiguous
  short8 b_q = *(const short8*)(Qb + (q0 + col) * 32 + g8);

  // Build G tables transposed: D[m=16t+grp*4+r][q=col] -> G[q][m]
  {
    const float* rels[2] = {relh_g, relw_g};
#pragma unroll
    for (int tb = 0; tb < 2; ++tb) {
      const float* relg = rels[tb];
#pragma unroll
      for (int t = 0; t < 4; ++t) {
        int m = 16 * t + col;
        int mc = m > 62 ? 62 : m;            // m=63 junk, never read
        const float* rp = relg + mc * 32 + g8;
        float4 f0 = *(const float4*)rp;
        float4 f1 = *(const float4*)(rp + 4);
        short8 ar;
        ar[0] = f2bs(f0.x); ar[1] = f2bs(f0.y);
        ar[2] = f2bs(f0.z); ar[3] = f2bs(f0.w);
        ar[4] = f2bs(f1.x); ar[5] = f2bs(f1.y);
        ar[6] = f2bs(f1.z); ar[7] = f2bs(f1.w);
        f32x4 d = __builtin_amdgcn_mfma_f32_16x16x32_bf16(
            ar, b_q, (f32x4){0.f, 0.f, 0.f, 0.f}, 0, 0, 0);
        short4v o;
        o[0] = f2bs(d[0]); o[1] = f2bs(d[1]);
        o[2] = f2bs(d[2]); o[3] = f2bs(d[3]);
        short* Gd = tb ? Gw_w : &Gh_s[w][0][0];
        *(short4v*)(Gd + col * 68 + 16 * t + grp * 4) = o;
      }
    }
  }
  __asm__ volatile("s_waitcnt lgkmcnt(0)" ::: "memory");

  // Per-lane Gw values are iteration-independent: kx = t*16+grp*4+r.
  float gw[8];
#pragma unroll
  for (int t = 0; t < 2; ++t)
#pragma unroll
    for (int r = 0; r < 4; ++r)
      gw[t * 4 + r] =
          bs2f(Gw_w[col * 68 + t * 16 + grp * 4 + r - j0 - col + 31]);

  const short8 a_one = {0x3F80, 0x3F80, 0x3F80, 0x3F80,
                        0x3F80, 0x3F80, 0x3F80, 0x3F80};

  f32x4 acc0 = {0.f, 0.f, 0.f, 0.f};   // O^T d = grp*4+r,     q = col
  f32x4 acc1 = {0.f, 0.f, 0.f, 0.f};   // O^T d = 16+grp*4+r
  f32x4 accl = {0.f, 0.f, 0.f, 0.f};   // l[q=col] in every reg

  short8 cvA0p = {}, cvA1p = {}, cvB0p = {}, cvB1p = {};  // carried V frags

  // commit iter-0 stage, make visible to all waves (drains gw reads too)
  *(short8*)&kvb[0][w][lane * 8] = stgK;
  *(short8*)&kvb[0][4 + w][lane * 8] = stgV;
  __syncthreads();

#pragma unroll 2
  for (int it = 0; it < 16; ++it) {
    const int cur = it & 1;
    if (it < 15) {
      stgK = *(const short8*)(gK + (size_t)(it + 1) * 2048);
      stgV = *(const short8*)(gV + (size_t)(it + 1) * 2048);
    }
    // 8 lane-linear conflict-free b128 reads
    short8 ck0  = *(const short8*)&kvb[cur][0][lane * 8];
    short8 ck1  = *(const short8*)&kvb[cur][1][lane * 8];
    short8 ck2  = *(const short8*)&kvb[cur][2][lane * 8];
    short8 ck3  = *(const short8*)&kvb[cur][3][lane * 8];
    short8 cva0 = *(const short8*)&kvb[cur][4][lane * 8];
    short8 cva1 = *(const short8*)&kvb[cur][5][lane * 8];
    short8 cvb0 = *(const short8*)&kvb[cur][6][lane * 8];
    short8 cvb1 = *(const short8*)&kvb[cur][7][lane * 8];

    // S^T[key][q] for 4 key-groups of 16
    f32x4 s0 = __builtin_amdgcn_mfma_f32_16x16x32_bf16(
        ck0, b_q, (f32x4){0.f, 0.f, 0.f, 0.f}, 0, 0, 0);
    f32x4 s1 = __builtin_amdgcn_mfma_f32_16x16x32_bf16(
        ck1, b_q, (f32x4){0.f, 0.f, 0.f, 0.f}, 0, 0, 0);
    f32x4 s2 = __builtin_amdgcn_mfma_f32_16x16x32_bf16(
        ck2, b_q, (f32x4){0.f, 0.f, 0.f, 0.f}, 0, 0, 0);
    f32x4 s3 = __builtin_amdgcn_mfma_f32_16x16x32_bf16(
        ck3, b_q, (f32x4){0.f, 0.f, 0.f, 0.f}, 0, 0, 0);

    // PV of previous iteration (P single-buffered, wave-private)
    if (it > 0) {
      short8 pA = *(const short8*)&Pt_s[w][0][col][g8];
      short8 pB = *(const short8*)&Pt_s[w][1][col][g8];
      acc0 = __builtin_amdgcn_mfma_f32_16x16x32_bf16(cvA0p, pA, acc0, 0, 0, 0);
      acc0 = __builtin_amdgcn_mfma_f32_16x16x32_bf16(cvB0p, pB, acc0, 0, 0, 0);
      acc1 = __builtin_amdgcn_mfma_f32_16x16x32_bf16(cvA1p, pA, acc1, 0, 0, 0);
      acc1 = __builtin_amdgcn_mfma_f32_16x16x32_bf16(cvB1p, pB, acc1, 0, 0, 0);
      accl = __builtin_amdgcn_mfma_f32_16x16x32_bf16(a_one, pA, accl, 0, 0, 0);
      accl = __builtin_amdgcn_mfma_f32_16x16x32_bf16(a_one, pB, accl, 0, 0, 0);
    }

    // softmax numerator for the two 32-key chunks of this iteration
    float ghA = bs2f(Gh_s[w][col][2 * it - i + 31]);
    float ghB = bs2f(Gh_s[w][col][2 * it + 1 - i + 31]);
    short4v p0, p1, p2, p3;
#pragma unroll
    for (int r = 0; r < 4; ++r) p0[r] = f2bs(__expf(s0[r] + ghA + gw[r]));
#pragma unroll
    for (int r = 0; r < 4; ++r) p1[r] = f2bs(__expf(s1[r] + ghA + gw[4 + r]));
#pragma unroll
    for (int r = 0; r < 4; ++r) p2[r] = f2bs(__expf(s2[r] + ghB + gw[r]));
#pragma unroll
    for (int r = 0; r < 4; ++r) p3[r] = f2bs(__expf(s3[r] + ghB + gw[4 + r]));
    *(short4v*)&Pt_s[w][0][col][grp * 4] = p0;
    *(short4v*)&Pt_s[w][0][col][16 + grp * 4] = p1;
    *(short4v*)&Pt_s[w][1][col][grp * 4] = p2;
    *(short4v*)&Pt_s[w][1][col][16 + grp * 4] = p3;

    if (it < 15) {
      *(short8*)&kvb[cur ^ 1][w][lane * 8] = stgK;
      *(short8*)&kvb[cur ^ 1][4 + w][lane * 8] = stgV;
    }
    cvA0p = cva0; cvA1p = cva1; cvB0p = cvb0; cvB1p = cvb1;
    __syncthreads();   // everyone done with kvb[cur]; next slot staged
  }

  // drain: PV of the last iteration
  {
    short8 pA = *(const short8*)&Pt_s[w][0][col][g8];
    short8 pB = *(const short8*)&Pt_s[w][1][col][g8];
    acc0 = __builtin_amdgcn_mfma_f32_16x16x32_bf16(cvA0p, pA, acc0, 0, 0, 0);
    acc0 = __builtin_amdgcn_mfma_f32_16x16x32_bf16(cvB0p, pB, acc0, 0, 0, 0);
    acc1 = __builtin_amdgcn_mfma_f32_16x16x32_bf16(cvA1p, pA, acc1, 0, 0, 0);
    acc1 = __builtin_amdgcn_mfma_f32_16x16x32_bf16(cvB1p, pB, acc1, 0, 0, 0);
    accl = __builtin_amdgcn_mfma_f32_16x16x32_bf16(a_one, pA, accl, 0, 0, 0);
    accl = __builtin_amdgcn_mfma_f32_16x16x32_bf16(a_one, pB, accl, 0, 0, 0);
  }

  // epilogue: write amt2 fragment-tiled: [bq][pb=qt][c8=nh][grp'][pcol][8].
  // ch = nh*32 + h16*16 + grp*4 + r -> grp' = h16*2 + (grp>>1),
  // j' = (grp&1)*4 + r -> short4 stores.
  float rn = 1.0f / accl[0];
  const int bq = bnh >> 3, nh = bnh & 7;
  short* amb = amt2 + (((size_t)bq * 64 + qt) * 8 + nh) * 512 +
               (grp >> 1) * 128 + col * 8 + (grp & 1) * 4;
  short4v o4a, o4b;
#pragma unroll
  for (int r = 0; r < 4; ++r) {
    o4a[r] = f2bs(acc0[r] * rn);
    o4b[r] = f2bs(acc1[r] * rn);
  }
  *(short4v*)&amb[0] = o4a;
  *(short4v*)&amb[256] = o4b;     // h16=1 -> +2*128
}

// ---------------------------------------------------------------------------
// Kernel 3 (v3): output projection, fp32 out channels [256,512).
// A from Wa2, B from amt2 -- both lane-linear.  grid (16, 2, 8), block 256.
// ---------------------------------------------------------------------------
__global__ __launch_bounds__(256) void proj_mfma(
    const short* __restrict__ Wa2, const short* __restrict__ amt2,
    const float* __restrict__ bias, float* __restrict__ out) {
  const int tid = threadIdx.x;
  const int w = tid >> 6, lane = tid & 63;
  const int col = lane & 15, grp = lane >> 4;
  const int b = blockIdx.z;
  const int bx = blockIdx.x;
  const int p0 = bx * 64;
  const int ob = blockIdx.y * 128 + w * 16;
  const int o16 = ob >> 4;

  const short* wbase = Wa2 + lane * 8;
  const short* xpb = amt2 + (((size_t)b * 64 + bx * 4) * 8) * 512 + lane * 8;

  f32x4 acc[2][4] = {};
#pragma unroll
  for (int c8 = 0; c8 < 8; ++c8) {
    short8 a0 = *(const short8*)(wbase + (size_t)(o16 * 8 + c8) * 512);
    short8 a1 = *(const short8*)(wbase + (size_t)((o16 + 4) * 8 + c8) * 512);
    short8 b0 = *(const short8*)(xpb + c8 * 512);
    short8 b1 = *(const short8*)(xpb + 4096 + c8 * 512);
    short8 b2 = *(const short8*)(xpb + 8192 + c8 * 512);
    short8 b3 = *(const short8*)(xpb + 12288 + c8 * 512);
    acc[0][0] = __builtin_amdgcn_mfma_f32_16x16x32_bf16(a0, b0, acc[0][0], 0, 0, 0);
    acc[0][1] = __builtin_amdgcn_mfma_f32_16x16x32_bf16(a0, b1, acc[0][1], 0, 0, 0);
    acc[0][2] = __builtin_amdgcn_mfma_f32_16x16x32_bf16(a0, b2, acc[0][2], 0, 0, 0);
    acc[0][3] = __builtin_amdgcn_mfma_f32_16x16x32_bf16(a0, b3, acc[0][3], 0, 0, 0);
    acc[1][0] = __builtin_amdgcn_mfma_f32_16x16x32_bf16(a1, b0, acc[1][0], 0, 0, 0);
    acc[1][1] = __builtin_amdgcn_mfma_f32_16x16x32_bf16(a1, b1, acc[1][1], 0, 0, 0);
    acc[1][2] = __builtin_amdgcn_mfma_f32_16x16x32_bf16(a1, b2, acc[1][2], 0, 0, 0);
    acc[1][3] = __builtin_amdgcn_mfma_f32_16x16x32_bf16(a1, b3, acc[1][3], 0, 0, 0);
  }

#pragma unroll
  for (int j = 0; j < 2; ++j) {
    const int obase = ob + j * 64 + grp * 4;   // + r gives o in [0,256)
    float bv[4];
#pragma unroll
    for (int r = 0; r < 4; ++r) bv[r] = bias[obase + r];
#pragma unroll
    for (int pp = 0; pp < 4; ++pp) {
      const int p = p0 + pp * 16 + col;
#pragma unroll
      for (int r = 0; r < 4; ++r)
        out[((size_t)b * 512 + 256 + obase + r) * 1024 + p] =
            acc[j][pp][r] + bv[r];
    }
  }
}

// ---------------------------------------------------------------------------
// Kernel 4 (v6): LDS-staged MFMA implicit-GEMM 3x3 conv; weights from Wb2
// lane-linear.  grid (32, 2, 8), block 256.
// ---------------------------------------------------------------------------
__global__ __launch_bounds__(256) void conv_mfma(
    const short* __restrict__ xt, const short* __restrict__ Wb2,
    const float* __restrict__ bias, float* __restrict__ out) {
  const int tid = threadIdx.x;
  const int w = tid >> 6, lane = tid & 63;
  const int col = lane & 15, grp = lane >> 4, g8 = grp * 8;
  const int r0 = blockIdx.x;            // output row 0..31
  const int oh = blockIdx.y;            // o half 0/1
  const int bb = blockIdx.z;

  __shared__ short xs[3][34][264];      // pitch 264: even bank spread

  {
    const short* src = xt + (((size_t)bb * 34 + r0) * 34) * 256;
    for (int g = tid; g < 3264; g += 256) {       // 3*34*32 8-short groups
      int row = g / 1088;                          // 34*32
      int rem = g - row * 1088;
      int cc = rem >> 5, chg = rem & 31;
      short8 v = *(const short8*)(src + (row * 34 + cc) * 256 + chg * 8);
      *(short8*)&xs[row][cc][chg * 8] = v;
    }
  }
  __syncthreads();

  const int ob0 = oh * 128 + w * 16;    // first o-tile
  const int o16_0 = oh * 8 + w;         // ob0>>4
  const short* wbase = Wb2 + lane * 8;

  f32x4 acc00 = {0.f, 0.f, 0.f, 0.f};
  f32x4 acc01 = {0.f, 0.f, 0.f, 0.f};
  f32x4 acc10 = {0.f, 0.f, 0.f, 0.f};
  f32x4 acc11 = {0.f, 0.f, 0.f, 0.f};

#pragma unroll 1
  for (int tap = 0; tap < 9; ++tap) {
    const int u = (tap * 11) >> 5, v = tap - 3 * u;   // exact for tap<9
    const short* wt = wbase + (size_t)tap * 65536;
    const short* xb0 = &xs[u][col + v][g8];
    const short* xb1 = &xs[u][col + 16 + v][g8];
#pragma unroll
    for (int c8 = 0; c8 < 8; ++c8) {
      const int chb = c8 * 32;
      short8 a0 = *(const short8*)(wt + (size_t)(o16_0 * 8 + c8) * 512);
      short8 a1 = *(const short8*)(wt + (size_t)((o16_0 + 4) * 8 + c8) * 512);
      short8 b0 = *(const short8*)(xb0 + chb);
      short8 b1 = *(const short8*)(xb1 + chb);
      acc00 = __builtin_amdgcn_mfma_f32_16x16x32_bf16(a0, b0, acc00, 0, 0, 0);
      acc01 = __builtin_amdgcn_mfma_f32_16x16x32_bf16(a0, b1, acc01, 0, 0, 0);
      acc10 = __builtin_amdgcn_mfma_f32_16x16x32_bf16(a1, b0, acc10, 0, 0, 0);
      acc11 = __builtin_amdgcn_mfma_f32_16x16x32_bf16(a1, b1, acc11, 0, 0, 0);
    }
  }

  const int ob1 = ob0 + 64;
  float* ob = out + (size_t)bb * 512 * 1024 + r0 * 32;
#pragma unroll
  for (int r = 0; r < 4; ++r) {
    int o0 = ob0 + grp * 4 + r;
    int o1 = ob1 + grp * 4 + r;
    float bv0 = bias[o0], bv1 = bias[o1];
    ob[(size_t)o0 * 1024 + col]      = acc00[r] + bv0;
    ob[(size_t)o0 * 1024 + 16 + col] = acc01[r] + bv0;
    ob[(size_t)o1 * 1024 + col]      = acc10[r] + bv1;
    ob[(size_t)o1 * 1024 + 16 + col] = acc11[r] + bv1;
  }
}

// ---------------------------------------------------------------------------
extern "C" void kernel_launch(void* const* d_in, const int* in_sizes, int n_in,
                              void* d_out, int out_size, void* d_ws, size_t ws_size,
                              hipStream_t stream) {
  const float* x      = (const float*)d_in[0];
  const float* w_qkv  = (const float*)d_in[1];
  const float* b_qkv  = (const float*)d_in[2];
  const float* w_attn = (const float*)d_in[3];
  const float* b_attn = (const float*)d_in[4];
  const float* w_out  = (const float*)d_in[5];
  const float* b_out  = (const float*)d_in[6];
  const float* relw   = (const float*)d_in[7];
  const float* relh   = (const float*)d_in[8];
  float* out = (float*)d_out;

  // ws layout (bytes):
  //   qsb bf16 4MB @0 | ksb2 4MB @4M | vtb2 4MB @8M | amt2 bf16 4MB @12M
  //   xt bf16 ~4.52MB @16M | xb2 bf16 4MB @21M
  //   Wq2 384KB @25M | Wa2 128KB @25.5M | Wb2 1.125MB @26M.  Total ~27.2MB.
  short* qsb  = (short*)d_ws;
  short* ksb2 = qsb + (size_t)2 * 1024 * 1024;
  short* vtb2 = ksb2 + (size_t)2 * 1024 * 1024;
  short* amt2 = (short*)((char*)d_ws + (size_t)12 * 1024 * 1024);
  short* xt   = (short*)((char*)d_ws + (size_t)16 * 1024 * 1024);
  short* xb2  = (short*)((char*)d_ws + (size_t)21 * 1024 * 1024);
  short* Wq2  = (short*)((char*)d_ws + (size_t)25 * 1024 * 1024);
  short* Wa2  = (short*)((char*)d_ws + (size_t)25 * 1024 * 1024 + 512 * 1024);
  short* Wb2  = (short*)((char*)d_ws + (size_t)26 * 1024 * 1024);

  xpose<<<dim3(8, 34), 256, 0, stream>>>(x, xt, xb2);
  wpack<<<1280, 256, 0, stream>>>(w_out, Wb2, w_qkv, Wq2, w_attn, Wa2);
  qkv_mfma<<<dim3(16, 6, 8), 256, 0, stream>>>(Wq2, xb2, b_qkv, qsb, ksb2, vtb2);
  attn_mfma<<<dim3(16, 64), 256, 0, stream>>>(qsb, ksb2, vtb2, relw, relh, amt2);
  proj_mfma<<<dim3(16, 2, 8), 256, 0, stream>>>(Wa2, amt2, b_attn, out);
  conv_mfma<<<dim3(32, 2, 8), 256, 0, stream>>>(xt, Wb2, b_out, out);
}

// Round 7
// 145.178 us; speedup vs baseline: 1.1889x; 1.0460x over previous
//
#include <hip/hip_runtime.h>
#include <hip/hip_bf16.h>

// Round-2 finding: ALL inputs and the output are FP32.
// Round-14: qkv/proj -> bf16 MFMA GEMMs (-33us).
// Round-15/16: coalesced xpose/wpack; fragment-tiled xb2 (-17us).
// Round-17/18: attn restructures -- NEUTRAL (serialization not the limit).
// Round-19: fragment-tiled ALL MFMA operands (-18us).
// Round-20 (this): kernel-time budget says ~60us of kernels vs 152us wall:
//   the addressable remainder is launch gaps (6 dependent dispatches).
//   Merge 6 -> 4: prep = xpose+wpack (blockIdx partition, LDS union),
//   tail = conv+proj (disjoint output channels).  Plus: fold log2(e) into
//   the q scale so attn uses raw v_exp_f32 (exp2) -- kills 16 v_mul per
//   lane-iter in the VALU-heaviest loop; G tables inherit the scale since
//   S and G are both built from the same scaled q.

typedef __hip_bfloat16 bf16;
using short8 = __attribute__((ext_vector_type(8))) short;
using short4v = __attribute__((ext_vector_type(4))) short;
using f32x4 = __attribute__((ext_vector_type(4))) float;

__device__ __forceinline__ short f2bs(float f) {
  union { bf16 b; short s; } u; u.b = __float2bfloat16(f); return u.s;
}
__device__ __forceinline__ float bs2f(short s) {
  union { unsigned u; float f; } x; x.u = ((unsigned)(unsigned short)s) << 16;
  return x.f;
}
__device__ __forceinline__ float fexp2(float x) {
  float r; asm("v_exp_f32 %0, %1" : "=v"(r) : "v"(x)); return r;
}

// Fragment-tile address for a [O][256] bf16 weight matrix:
// frag (o16 = o>>4, c8 = c>>5), lane (col = o&15, grp = (c>>3)&3), j = c&7.
__device__ __forceinline__ size_t wtile(int o, int c) {
  return ((size_t)((o >> 4) * 8 + (c >> 5)) * 512) +
         (((c >> 3) & 3) * 16 + (o & 15)) * 8 + (c & 7);
}

// ---------------------------------------------------------------------------
// Kernel 0 (prep): xpose + all weight packs, blockIdx-partitioned.
//   bid [0,272):    xpose row (b = bid/34, r = bid%34)
//   bid [272,528):  conv weight pack (o = bid-272) -> Wb2 fragment-tiled
//   bid [528,1296): Wq2 pack (o = bid-528)
//   bid [1296,1552): Wa2 pack (o = bid-1296)
// grid 1552, block 256.  LDS: union of xls (16896B) / ws (9216B).
// ---------------------------------------------------------------------------
__global__ __launch_bounds__(256) void prep(
    const float* __restrict__ X, short* __restrict__ xt,
    short* __restrict__ xb2,
    const float* __restrict__ Wc, short* __restrict__ Wb2,
    const float* __restrict__ wq, short* __restrict__ Wq2,
    const float* __restrict__ wa, short* __restrict__ Wa2) {
  __shared__ char smem[16896];
  const int bid = blockIdx.x;
  const int tid = threadIdx.x;
  if (bid < 272) {
    const int b = bid / 34, r = bid - (bid / 34) * 34;   // r in 0..33
    if (r == 0 || r == 33) {                  // full zero halo row
      short8 z = {};
      short* dst = xt + (((size_t)b * 34 + r) * 34) * 256;
      for (int g = tid; g < 1088; g += 256) *(short8*)(dst + g * 8) = z;
      return;
    }
    short (*xls)[264] = (short(*)[264])smem;  // [p][c], pitch 264
    {
      const float* src = X + (size_t)b * 256 * 1024 + (r - 1) * 32;
      for (int it = 0; it < 8; ++it) {
        int idx = it * 256 + tid;
        int c = idx >> 3, pq = idx & 7;
        float4 f4 = *(const float4*)(src + (size_t)c * 1024 + pq * 4);
        xls[pq * 4 + 0][c] = f2bs(f4.x);
        xls[pq * 4 + 1][c] = f2bs(f4.y);
        xls[pq * 4 + 2][c] = f2bs(f4.z);
        xls[pq * 4 + 3][c] = f2bs(f4.w);
      }
    }
    __syncthreads();
    {
      short* dst = xt + (((size_t)b * 34 + r) * 34) * 256;
      for (int it = 0; it < 4; ++it) {
        int idx = it * 256 + tid;
        int cc = idx >> 5, co = idx & 31;
        short8 v = *(const short8*)&xls[cc][co * 8];
        *(short8*)(dst + (cc + 1) * 256 + co * 8) = v;
      }
      if (tid < 64) {
        short8 z = {};
        int cce = (tid >> 5) * 33, co = tid & 31;
        *(short8*)(dst + cce * 256 + co * 8) = z;
      }
    }
    {
      short* dst = xb2 + (((size_t)b * 64 + (r - 1) * 2) * 8) * 512;
      for (int it = 0; it < 4; ++it) {
        int g = it * 256 + tid;
        int half = g >> 9, c8 = (g >> 6) & 7, grp = (g >> 4) & 3, pcol = g & 15;
        short8 v = *(const short8*)&xls[half * 16 + pcol][c8 * 32 + grp * 8];
        *(short8*)(dst + ((half * 8 + c8) * 64 + grp * 16 + pcol) * 8) = v;
      }
    }
  } else if (bid < 528) {
    float* ws = (float*)smem;                  // one o's [c][tap] block
    const int o = bid - 272;
    const float* src = Wc + (size_t)o * 2304;
    for (int it = 0; it < 9; ++it) ws[it * 256 + tid] = src[it * 256 + tid];
    __syncthreads();
#pragma unroll
    for (int tap = 0; tap < 9; ++tap)
      Wb2[(size_t)tap * 65536 + wtile(o, tid)] = f2bs(ws[tid * 9 + tap]);
  } else if (bid < 1296) {
    const int o = bid - 528;
    Wq2[wtile(o, tid)] = f2bs(wq[o * 256 + tid]);
  } else {
    const int o = bid - 1296;
    Wa2[wtile(o, tid)] = f2bs(wa[o * 256 + tid]);
  }
}

// ---------------------------------------------------------------------------
// Kernel 1 (v11): QKV 1x1 conv as bf16 MFMA GEMM, all operands lane-linear.
// q-scale now includes log2(e) so attn can use raw exp2.
// grid (16, 6, 8), block 256.
// ---------------------------------------------------------------------------
__global__ __launch_bounds__(256) void qkv_mfma(
    const short* __restrict__ Wq2, const short* __restrict__ xb2,
    const float* __restrict__ bias,
    short* __restrict__ qsb, short* __restrict__ ksb2, short* __restrict__ vtb2) {
  const int tid = threadIdx.x;
  const int w = tid >> 6, lane = tid & 63;
  const int col = lane & 15, grp = lane >> 4;
  const int b = blockIdx.z;
  const int bx = blockIdx.x;
  const int p0 = bx * 64;
  const int ob = blockIdx.y * 128 + w * 16;
  const int o16 = ob >> 4;                    // = by*8 + w

  const short* wbase = Wq2 + lane * 8;
  const short* xpb = xb2 + (((size_t)b * 64 + bx * 4) * 8) * 512 + lane * 8;

  f32x4 acc[2][4] = {};
#pragma unroll
  for (int c8 = 0; c8 < 8; ++c8) {
    short8 a0 = *(const short8*)(wbase + (size_t)(o16 * 8 + c8) * 512);
    short8 a1 = *(const short8*)(wbase + (size_t)((o16 + 4) * 8 + c8) * 512);
    short8 b0 = *(const short8*)(xpb + c8 * 512);
    short8 b1 = *(const short8*)(xpb + 4096 + c8 * 512);
    short8 b2 = *(const short8*)(xpb + 8192 + c8 * 512);
    short8 b3 = *(const short8*)(xpb + 12288 + c8 * 512);
    acc[0][0] = __builtin_amdgcn_mfma_f32_16x16x32_bf16(a0, b0, acc[0][0], 0, 0, 0);
    acc[0][1] = __builtin_amdgcn_mfma_f32_16x16x32_bf16(a0, b1, acc[0][1], 0, 0, 0);
    acc[0][2] = __builtin_amdgcn_mfma_f32_16x16x32_bf16(a0, b2, acc[0][2], 0, 0, 0);
    acc[0][3] = __builtin_amdgcn_mfma_f32_16x16x32_bf16(a0, b3, acc[0][3], 0, 0, 0);
    acc[1][0] = __builtin_amdgcn_mfma_f32_16x16x32_bf16(a1, b0, acc[1][0], 0, 0, 0);
    acc[1][1] = __builtin_amdgcn_mfma_f32_16x16x32_bf16(a1, b1, acc[1][1], 0, 0, 0);
    acc[1][2] = __builtin_amdgcn_mfma_f32_16x16x32_bf16(a1, b2, acc[1][2], 0, 0, 0);
    acc[1][3] = __builtin_amdgcn_mfma_f32_16x16x32_bf16(a1, b3, acc[1][3], 0, 0, 0);
  }

  const float qscale = 0.25503486f;  // 32^-0.5 * log2(e)
#pragma unroll
  for (int j = 0; j < 2; ++j) {
    const int obase = ob + j * 64 + grp * 4;   // + r gives the output chan
    const int sect = obase >> 8;               // 0=q 1=k 2=v (tile-uniform)
    const int nh = (obase >> 5) & 7;
    const int d0 = obase & 31;                 // d0..d0+3 consecutive
    const size_t hb = ((size_t)(b * 8 + nh)) * 1024;    // qsb base
    const size_t hb2 = ((size_t)(b * 8 + nh)) * 32768;  // ksb2/vtb2 base
    float bv[4];
#pragma unroll
    for (int r = 0; r < 4; ++r) bv[r] = bias[obase + r];
    if (sect == 0) {
#pragma unroll
      for (int pp = 0; pp < 4; ++pp) {
        const int p = p0 + pp * 16 + col;
        short4v o4;
#pragma unroll
        for (int r = 0; r < 4; ++r)
          o4[r] = f2bs((acc[j][pp][r] + bv[r]) * qscale);
        *(short4v*)&qsb[(hb + p) * 32 + d0] = o4;
      }
    } else if (sect == 1) {
      // ksb2[bnh][kit=bx][frag=pp][lane'][j'] (kvb staging layout)
      const size_t kb = hb2 + (size_t)bx * 2048 + (w & 1) * 256 +
                        (grp >> 1) * 128 + col * 8 + (grp & 1) * 4;
#pragma unroll
      for (int pp = 0; pp < 4; ++pp) {
        short4v o4;
#pragma unroll
        for (int r = 0; r < 4; ++r)
          o4[r] = f2bs(acc[j][pp][r] + bv[r]);
        *(short4v*)&ksb2[kb + pp * 512] = o4;
      }
    } else {
      // vtb2[bnh][kit=bx][frag][lane'][j'] (kvb staging layout)
      const size_t vb0 = hb2 + (size_t)bx * 2048 + (size_t)(w & 1) * 512 +
                         (col >> 3) * 128 + (grp * 4) * 8 + (col & 7);
#pragma unroll
      for (int pp = 0; pp < 4; ++pp) {
        const size_t vb = vb0 + (pp >> 1) * 1024 + (pp & 1) * 256;
#pragma unroll
        for (int r = 0; r < 4; ++r)
          vtb2[vb + r * 8] = f2bs(acc[j][pp][r] + bv[r]);
      }
    }
  }
}

// ---------------------------------------------------------------------------
// Kernel 2 (v11): pipelined transposed MFMA flash attention; lane-linear
// K/V staging; softmax via raw v_exp_f32 (inputs pre-scaled by log2e).
// grid (16, 64), block 256 = 4 waves.  LDS 35.3KB -> 4 blocks/CU.
// ---------------------------------------------------------------------------
__global__ __launch_bounds__(256, 4) void attn_mfma(
    const short* __restrict__ qsb, const short* __restrict__ ksb2,
    const short* __restrict__ vtb2,
    const float* __restrict__ relw_g, const float* __restrict__ relh_g,
    short* __restrict__ amt2) {
  const int tid = threadIdx.x;
  const int w = tid >> 6, lane = tid & 63;
  const int col = lane & 15, grp = lane >> 4, g8 = grp * 8;
  const int qt = blockIdx.x * 4 + w;       // q-tile 0..63
  const int bnh = blockIdx.y;
  const int q0 = qt * 16;
  const int i = qt >> 1;                   // query row, constant per wave
  const int j0 = (qt & 1) * 16;            // query col base

  const short* Qb = qsb + (size_t)bnh * 32768;

  __shared__ short Gh_s[4][16][68];     // [wave][q][m]        8704B
  __shared__ short kvb[2][8][512];      // [slot][frag][...]  16384B
  __shared__ short Pt_s[4][2][16][40];  // [wave][half][q][key] 10240B
  short* Gw_w = &Pt_s[w][0][0][0];      // scratch alias (wave-private)

  // lane-linear staging sources (one 1KB transaction per instruction)
  const short* gK = ksb2 + (size_t)bnh * 32768 + w * 512 + lane * 8;
  const short* gV = vtb2 + (size_t)bnh * 32768 + w * 512 + lane * 8;

  short8 stgK = *(const short8*)gK;            // iter-0 frags (in flight)
  short8 stgV = *(const short8*)gV;

  // Q as B-operand fragment (Q^T[k=d][n=q]); 16B contiguous
  short8 b_q = *(const short8*)(Qb + (q0 + col) * 32 + g8);

  // Build G tables transposed: D[m=16t+grp*4+r][q=col] -> G[q][m]
  // (G inherits the log2e scale through b_q.)
  {
    const float* rels[2] = {relh_g, relw_g};
#pragma unroll
    for (int tb = 0; tb < 2; ++tb) {
      const float* relg = rels[tb];
#pragma unroll
      for (int t = 0; t < 4; ++t) {
        int m = 16 * t + col;
        int mc = m > 62 ? 62 : m;            // m=63 junk, never read
        const float* rp = relg + mc * 32 + g8;
        float4 f0 = *(const float4*)rp;
        float4 f1 = *(const float4*)(rp + 4);
        short8 ar;
        ar[0] = f2bs(f0.x); ar[1] = f2bs(f0.y);
        ar[2] = f2bs(f0.z); ar[3] = f2bs(f0.w);
        ar[4] = f2bs(f1.x); ar[5] = f2bs(f1.y);
        ar[6] = f2bs(f1.z); ar[7] = f2bs(f1.w);
        f32x4 d = __builtin_amdgcn_mfma_f32_16x16x32_bf16(
            ar, b_q, (f32x4){0.f, 0.f, 0.f, 0.f}, 0, 0, 0);
        short4v o;
        o[0] = f2bs(d[0]); o[1] = f2bs(d[1]);
        o[2] = f2bs(d[2]); o[3] = f2bs(d[3]);
        short* Gd = tb ? Gw_w : &Gh_s[w][0][0];
        *(short4v*)(Gd + col * 68 + 16 * t + grp * 4) = o;
      }
    }
  }
  __asm__ volatile("s_waitcnt lgkmcnt(0)" ::: "memory");

  // Per-lane Gw values are iteration-independent: kx = t*16+grp*4+r.
  float gw[8];
#pragma unroll
  for (int t = 0; t < 2; ++t)
#pragma unroll
    for (int r = 0; r < 4; ++r)
      gw[t * 4 + r] =
          bs2f(Gw_w[col * 68 + t * 16 + grp * 4 + r - j0 - col + 31]);

  const short8 a_one = {0x3F80, 0x3F80, 0x3F80, 0x3F80,
                        0x3F80, 0x3F80, 0x3F80, 0x3F80};

  f32x4 acc0 = {0.f, 0.f, 0.f, 0.f};   // O^T d = grp*4+r,     q = col
  f32x4 acc1 = {0.f, 0.f, 0.f, 0.f};   // O^T d = 16+grp*4+r
  f32x4 accl = {0.f, 0.f, 0.f, 0.f};   // l[q=col] in every reg

  short8 cvA0p = {}, cvA1p = {}, cvB0p = {}, cvB1p = {};  // carried V frags

  // commit iter-0 stage, make visible to all waves (drains gw reads too)
  *(short8*)&kvb[0][w][lane * 8] = stgK;
  *(short8*)&kvb[0][4 + w][lane * 8] = stgV;
  __syncthreads();

#pragma unroll 2
  for (int it = 0; it < 16; ++it) {
    const int cur = it & 1;
    if (it < 15) {
      stgK = *(const short8*)(gK + (size_t)(it + 1) * 2048);
      stgV = *(const short8*)(gV + (size_t)(it + 1) * 2048);
    }
    // 8 lane-linear conflict-free b128 reads
    short8 ck0  = *(const short8*)&kvb[cur][0][lane * 8];
    short8 ck1  = *(const short8*)&kvb[cur][1][lane * 8];
    short8 ck2  = *(const short8*)&kvb[cur][2][lane * 8];
    short8 ck3  = *(const short8*)&kvb[cur][3][lane * 8];
    short8 cva0 = *(const short8*)&kvb[cur][4][lane * 8];
    short8 cva1 = *(const short8*)&kvb[cur][5][lane * 8];
    short8 cvb0 = *(const short8*)&kvb[cur][6][lane * 8];
    short8 cvb1 = *(const short8*)&kvb[cur][7][lane * 8];

    // S^T[key][q] for 4 key-groups of 16
    f32x4 s0 = __builtin_amdgcn_mfma_f32_16x16x32_bf16(
        ck0, b_q, (f32x4){0.f, 0.f, 0.f, 0.f}, 0, 0, 0);
    f32x4 s1 = __builtin_amdgcn_mfma_f32_16x16x32_bf16(
        ck1, b_q, (f32x4){0.f, 0.f, 0.f, 0.f}, 0, 0, 0);
    f32x4 s2 = __builtin_amdgcn_mfma_f32_16x16x32_bf16(
        ck2, b_q, (f32x4){0.f, 0.f, 0.f, 0.f}, 0, 0, 0);
    f32x4 s3 = __builtin_amdgcn_mfma_f32_16x16x32_bf16(
        ck3, b_q, (f32x4){0.f, 0.f, 0.f, 0.f}, 0, 0, 0);

    // PV of previous iteration (P single-buffered, wave-private)
    if (it > 0) {
      short8 pA = *(const short8*)&Pt_s[w][0][col][g8];
      short8 pB = *(const short8*)&Pt_s[w][1][col][g8];
      acc0 = __builtin_amdgcn_mfma_f32_16x16x32_bf16(cvA0p, pA, acc0, 0, 0, 0);
      acc0 = __builtin_amdgcn_mfma_f32_16x16x32_bf16(cvB0p, pB, acc0, 0, 0, 0);
      acc1 = __builtin_amdgcn_mfma_f32_16x16x32_bf16(cvA1p, pA, acc1, 0, 0, 0);
      acc1 = __builtin_amdgcn_mfma_f32_16x16x32_bf16(cvB1p, pB, acc1, 0, 0, 0);
      accl = __builtin_amdgcn_mfma_f32_16x16x32_bf16(a_one, pA, accl, 0, 0, 0);
      accl = __builtin_amdgcn_mfma_f32_16x16x32_bf16(a_one, pB, accl, 0, 0, 0);
    }

    // softmax numerator (all inputs pre-scaled by log2e -> raw exp2)
    float ghA = bs2f(Gh_s[w][col][2 * it - i + 31]);
    float ghB = bs2f(Gh_s[w][col][2 * it + 1 - i + 31]);
    short4v p0, p1, p2, p3;
#pragma unroll
    for (int r = 0; r < 4; ++r) p0[r] = f2bs(fexp2(s0[r] + ghA + gw[r]));
#pragma unroll
    for (int r = 0; r < 4; ++r) p1[r] = f2bs(fexp2(s1[r] + ghA + gw[4 + r]));
#pragma unroll
    for (int r = 0; r < 4; ++r) p2[r] = f2bs(fexp2(s2[r] + ghB + gw[r]));
#pragma unroll
    for (int r = 0; r < 4; ++r) p3[r] = f2bs(fexp2(s3[r] + ghB + gw[4 + r]));
    *(short4v*)&Pt_s[w][0][col][grp * 4] = p0;
    *(short4v*)&Pt_s[w][0][col][16 + grp * 4] = p1;
    *(short4v*)&Pt_s[w][1][col][grp * 4] = p2;
    *(short4v*)&Pt_s[w][1][col][16 + grp * 4] = p3;

    if (it < 15) {
      *(short8*)&kvb[cur ^ 1][w][lane * 8] = stgK;
      *(short8*)&kvb[cur ^ 1][4 + w][lane * 8] = stgV;
    }
    cvA0p = cva0; cvA1p = cva1; cvB0p = cvb0; cvB1p = cvb1;
    __syncthreads();   // everyone done with kvb[cur]; next slot staged
  }

  // drain: PV of the last iteration
  {
    short8 pA = *(const short8*)&Pt_s[w][0][col][g8];
    short8 pB = *(const short8*)&Pt_s[w][1][col][g8];
    acc0 = __builtin_amdgcn_mfma_f32_16x16x32_bf16(cvA0p, pA, acc0, 0, 0, 0);
    acc0 = __builtin_amdgcn_mfma_f32_16x16x32_bf16(cvB0p, pB, acc0, 0, 0, 0);
    acc1 = __builtin_amdgcn_mfma_f32_16x16x32_bf16(cvA1p, pA, acc1, 0, 0, 0);
    acc1 = __builtin_amdgcn_mfma_f32_16x16x32_bf16(cvB1p, pB, acc1, 0, 0, 0);
    accl = __builtin_amdgcn_mfma_f32_16x16x32_bf16(a_one, pA, accl, 0, 0, 0);
    accl = __builtin_amdgcn_mfma_f32_16x16x32_bf16(a_one, pB, accl, 0, 0, 0);
  }

  // epilogue: write amt2 fragment-tiled (short4 stores).
  float rn = 1.0f / accl[0];
  const int bq = bnh >> 3, nh = bnh & 7;
  short* amb = amt2 + (((size_t)bq * 64 + qt) * 8 + nh) * 512 +
               (grp >> 1) * 128 + col * 8 + (grp & 1) * 4;
  short4v o4a, o4b;
#pragma unroll
  for (int r = 0; r < 4; ++r) {
    o4a[r] = f2bs(acc0[r] * rn);
    o4b[r] = f2bs(acc1[r] * rn);
  }
  *(short4v*)&amb[0] = o4a;
  *(short4v*)&amb[256] = o4b;     // h16=1 -> +2*128
}

// ---------------------------------------------------------------------------
// Kernel 3 (tail): conv (bid<512, out ch [0,256)) + proj (bid>=512,
// out ch [256,512)), blockIdx-partitioned.  grid 768, block 256.
// ---------------------------------------------------------------------------
__global__ __launch_bounds__(256) void tail(
    const short* __restrict__ xt, const short* __restrict__ Wb2,
    const float* __restrict__ b_out,
    const short* __restrict__ Wa2, const short* __restrict__ amt2,
    const float* __restrict__ b_attn, float* __restrict__ out) {
  __shared__ short xs[3][34][264];      // conv staging; unused by proj
  const int bid = blockIdx.x;
  const int tid = threadIdx.x;
  const int w = tid >> 6, lane = tid & 63;
  const int col = lane & 15, grp = lane >> 4, g8 = grp * 8;

  if (bid < 512) {
    // ---- conv path ----
    const int r0 = bid & 31, oh = (bid >> 5) & 1, bb = bid >> 6;
    {
      const short* src = xt + (((size_t)bb * 34 + r0) * 34) * 256;
      for (int g = tid; g < 3264; g += 256) {       // 3*34*32 8-short groups
        int row = g / 1088;                          // 34*32
        int rem = g - row * 1088;
        int cc = rem >> 5, chg = rem & 31;
        short8 v = *(const short8*)(src + (row * 34 + cc) * 256 + chg * 8);
        *(short8*)&xs[row][cc][chg * 8] = v;
      }
    }
    __syncthreads();

    const int ob0 = oh * 128 + w * 16;    // first o-tile
    const int o16_0 = oh * 8 + w;         // ob0>>4
    const short* wbase = Wb2 + lane * 8;

    f32x4 acc00 = {0.f, 0.f, 0.f, 0.f};
    f32x4 acc01 = {0.f, 0.f, 0.f, 0.f};
    f32x4 acc10 = {0.f, 0.f, 0.f, 0.f};
    f32x4 acc11 = {0.f, 0.f, 0.f, 0.f};

#pragma unroll 1
    for (int tap = 0; tap < 9; ++tap) {
      const int u = (tap * 11) >> 5, v = tap - 3 * u;   // exact for tap<9
      const short* wt = wbase + (size_t)tap * 65536;
      const short* xb0 = &xs[u][col + v][g8];
      const short* xb1 = &xs[u][col + 16 + v][g8];
#pragma unroll
      for (int c8 = 0; c8 < 8; ++c8) {
        const int chb = c8 * 32;
        short8 a0 = *(const short8*)(wt + (size_t)(o16_0 * 8 + c8) * 512);
        short8 a1 = *(const short8*)(wt + (size_t)((o16_0 + 4) * 8 + c8) * 512);
        short8 b0 = *(const short8*)(xb0 + chb);
        short8 b1 = *(const short8*)(xb1 + chb);
        acc00 = __builtin_amdgcn_mfma_f32_16x16x32_bf16(a0, b0, acc00, 0, 0, 0);
        acc01 = __builtin_amdgcn_mfma_f32_16x16x32_bf16(a0, b1, acc01, 0, 0, 0);
        acc10 = __builtin_amdgcn_mfma_f32_16x16x32_bf16(a1, b0, acc10, 0, 0, 0);
        acc11 = __builtin_amdgcn_mfma_f32_16x16x32_bf16(a1, b1, acc11, 0, 0, 0);
      }
    }

    const int ob1 = ob0 + 64;
    float* ob = out + (size_t)bb * 512 * 1024 + r0 * 32;
#pragma unroll
    for (int r = 0; r < 4; ++r) {
      int o0 = ob0 + grp * 4 + r;
      int o1 = ob1 + grp * 4 + r;
      float bv0 = b_out[o0], bv1 = b_out[o1];
      ob[(size_t)o0 * 1024 + col]      = acc00[r] + bv0;
      ob[(size_t)o0 * 1024 + 16 + col] = acc01[r] + bv0;
      ob[(size_t)o1 * 1024 + col]      = acc10[r] + bv1;
      ob[(size_t)o1 * 1024 + 16 + col] = acc11[r] + bv1;
    }
  } else {
    // ---- proj path ----
    const int t = bid - 512;
    const int bx = t & 15, by = (t >> 4) & 1, b = t >> 5;
    const int p0 = bx * 64;
    const int ob = by * 128 + w * 16;
    const int o16 = ob >> 4;

    const short* wbase = Wa2 + lane * 8;
    const short* xpb = amt2 + (((size_t)b * 64 + bx * 4) * 8) * 512 + lane * 8;

    f32x4 acc[2][4] = {};
#pragma unroll
    for (int c8 = 0; c8 < 8; ++c8) {
      short8 a0 = *(const short8*)(wbase + (size_t)(o16 * 8 + c8) * 512);
      short8 a1 = *(const short8*)(wbase + (size_t)((o16 + 4) * 8 + c8) * 512);
      short8 b0 = *(const short8*)(xpb + c8 * 512);
      short8 b1 = *(const short8*)(xpb + 4096 + c8 * 512);
      short8 b2 = *(const short8*)(xpb + 8192 + c8 * 512);
      short8 b3 = *(const short8*)(xpb + 12288 + c8 * 512);
      acc[0][0] = __builtin_amdgcn_mfma_f32_16x16x32_bf16(a0, b0, acc[0][0], 0, 0, 0);
      acc[0][1] = __builtin_amdgcn_mfma_f32_16x16x32_bf16(a0, b1, acc[0][1], 0, 0, 0);
      acc[0][2] = __builtin_amdgcn_mfma_f32_16x16x32_bf16(a0, b2, acc[0][2], 0, 0, 0);
      acc[0][3] = __builtin_amdgcn_mfma_f32_16x16x32_bf16(a0, b3, acc[0][3], 0, 0, 0);
      acc[1][0] = __builtin_amdgcn_mfma_f32_16x16x32_bf16(a1, b0, acc[1][0], 0, 0, 0);
      acc[1][1] = __builtin_amdgcn_mfma_f32_16x16x32_bf16(a1, b1, acc[1][1], 0, 0, 0);
      acc[1][2] = __builtin_amdgcn_mfma_f32_16x16x32_bf16(a1, b2, acc[1][2], 0, 0, 0);
      acc[1][3] = __builtin_amdgcn_mfma_f32_16x16x32_bf16(a1, b3, acc[1][3], 0, 0, 0);
    }

#pragma unroll
    for (int j = 0; j < 2; ++j) {
      const int obase = ob + j * 64 + grp * 4;   // + r gives o in [0,256)
      float bv[4];
#pragma unroll
      for (int r = 0; r < 4; ++r) bv[r] = b_attn[obase + r];
#pragma unroll
      for (int pp = 0; pp < 4; ++pp) {
        const int p = p0 + pp * 16 + col;
#pragma unroll
        for (int r = 0; r < 4; ++r)
          out[((size_t)b * 512 + 256 + obase + r) * 1024 + p] =
              acc[j][pp][r] + bv[r];
      }
    }
  }
}

// ---------------------------------------------------------------------------
extern "C" void kernel_launch(void* const* d_in, const int* in_sizes, int n_in,
                              void* d_out, int out_size, void* d_ws, size_t ws_size,
                              hipStream_t stream) {
  const float* x      = (const float*)d_in[0];
  const float* w_qkv  = (const float*)d_in[1];
  const float* b_qkv  = (const float*)d_in[2];
  const float* w_attn = (const float*)d_in[3];
  const float* b_attn = (const float*)d_in[4];
  const float* w_out  = (const float*)d_in[5];
  const float* b_out  = (const float*)d_in[6];
  const float* relw   = (const float*)d_in[7];
  const float* relh   = (const float*)d_in[8];
  float* out = (float*)d_out;

  // ws layout (bytes):
  //   qsb bf16 4MB @0 | ksb2 4MB @4M | vtb2 4MB @8M | amt2 bf16 4MB @12M
  //   xt bf16 ~4.52MB @16M | xb2 bf16 4MB @21M
  //   Wq2 384KB @25M | Wa2 128KB @25.5M | Wb2 1.125MB @26M.  Total ~27.2MB.
  short* qsb  = (short*)d_ws;
  short* ksb2 = qsb + (size_t)2 * 1024 * 1024;
  short* vtb2 = ksb2 + (size_t)2 * 1024 * 1024;
  short* amt2 = (short*)((char*)d_ws + (size_t)12 * 1024 * 1024);
  short* xt   = (short*)((char*)d_ws + (size_t)16 * 1024 * 1024);
  short* xb2  = (short*)((char*)d_ws + (size_t)21 * 1024 * 1024);
  short* Wq2  = (short*)((char*)d_ws + (size_t)25 * 1024 * 1024);
  short* Wa2  = (short*)((char*)d_ws + (size_t)25 * 1024 * 1024 + 512 * 1024);
  short* Wb2  = (short*)((char*)d_ws + (size_t)26 * 1024 * 1024);

  prep<<<1552, 256, 0, stream>>>(x, xt, xb2, w_out, Wb2, w_qkv, Wq2,
                                 w_attn, Wa2);
  qkv_mfma<<<dim3(16, 6, 8), 256, 0, stream>>>(Wq2, xb2, b_qkv, qsb, ksb2, vtb2);
  attn_mfma<<<dim3(16, 64), 256, 0, stream>>>(qsb, ksb2, vtb2, relw, relh, amt2);
  tail<<<768, 256, 0, stream>>>(xt, Wb2, b_out, Wa2, amt2, b_attn, out);
}